// Round 5
// baseline (451.479 us; speedup 1.0000x reference)
//
#include <hip/hip_runtime.h>

#define PRE_K 1000
#define CAP   2048      // candidate buffer per level (>= PRE_K + max bin, pow2)
#define NBIN  8192      // 13-bit key-prefix histogram bins
#define NB    1000      // boxes per level after pre-NMS topk
#define NW    16        // 64-bit words covering NB bits (16*64 = 1024)
#define TOT   4000      // concatenated entries per batch
#define TOTP  4096      // padded pow2 for bitonic
#define NLVL  4
#define BATCH 8
#define HB    8         // blocks per (b,lvl) for hist/collect

__device__ __forceinline__ unsigned f2key(float f) {
    unsigned u = __float_as_uint(f);
    return (u & 0x80000000u) ? ~u : (u | 0x80000000u);   // monotonic ascending
}
__device__ __forceinline__ float key2f(unsigned k) {
    unsigned u = (k & 0x80000000u) ? (k & 0x7FFFFFFFu) : ~k;
    return __uint_as_float(u);
}
__device__ __forceinline__ const float* lvl_scores(
    const float* s0, const float* s1, const float* s2, const float* s3, int lvl) {
    switch (lvl) { case 0: return s0; case 1: return s1; case 2: return s2; default: return s3; }
}
__device__ __forceinline__ const float* lvl_boxes(
    const float* b0, const float* b1, const float* b2, const float* b3, int lvl) {
    switch (lvl) { case 0: return b0; case 1: return b1; case 2: return b2; default: return b3; }
}
__device__ __forceinline__ int lvl_n(int lvl) {
    const int sizes[4] = {196608, 49152, 12288, 3072};
    return sizes[lvl];
}

// ---------------------------------------------------------------------------
// T0: zero global histograms
// ---------------------------------------------------------------------------
__global__ __launch_bounds__(512) void init_kernel(unsigned* __restrict__ ghist) {
    const int stride = gridDim.x * 512;
    for (int i = blockIdx.x * 512 + threadIdx.x; i < 32 * NBIN; i += stride)
        ghist[i] = 0u;
}

// ---------------------------------------------------------------------------
// T1: per-(b,lvl) 13-bit-prefix histogram. float4 loads; 2 bank-replicas to
// halve hot-bin LDS atomic serialization (N(0,1) scores concentrate bins).
// ---------------------------------------------------------------------------
__global__ __launch_bounds__(512) void hist_kernel(
    const float* __restrict__ scores0, const float* __restrict__ scores1,
    const float* __restrict__ scores2, const float* __restrict__ scores3,
    unsigned* __restrict__ ghist)      // [32][NBIN]
{
    const int blk = blockIdx.x / HB;   // b*4 + lvl
    const int hb  = blockIdx.x % HB;
    const int b   = blk >> 2;
    const int lvl = blk & 3;
    const int n   = lvl_n(lvl);
    const float* sc = lvl_scores(scores0, scores1, scores2, scores3, lvl) + (size_t)b * n;

    __shared__ unsigned lhist[2][NBIN];   // 64 KB
    const int tid = threadIdx.x;
    const int rep = (tid >> 6) & 1;       // wave-uniform replica
    for (int i = tid; i < 2 * NBIN; i += 512) (&lhist[0][0])[i] = 0u;
    __syncthreads();

    const float4* sc4 = (const float4*)sc;
    const int n4 = n >> 2;                // all level sizes divisible by 4
    for (int i = hb * 512 + tid; i < n4; i += HB * 512) {
        float4 v = sc4[i];
        atomicAdd(&lhist[rep][f2key(v.x) >> 19], 1u);
        atomicAdd(&lhist[rep][f2key(v.y) >> 19], 1u);
        atomicAdd(&lhist[rep][f2key(v.z) >> 19], 1u);
        atomicAdd(&lhist[rep][f2key(v.w) >> 19], 1u);
    }
    __syncthreads();

    unsigned* gh = ghist + (size_t)blk * NBIN;
    for (int i = tid; i < NBIN; i += 512) {
        unsigned v = lhist[0][i] + lhist[1][i];
        if (v) atomicAdd(&gh[i], v);
    }
}

// ---------------------------------------------------------------------------
// T2: per-(b,lvl) threshold-bin selection (top-PRE_K boundary); zero counters
// ---------------------------------------------------------------------------
__global__ __launch_bounds__(256) void select_kernel(
    const unsigned* __restrict__ ghist,   // [32][NBIN]
    unsigned* __restrict__ thresh,        // [32]
    unsigned* __restrict__ counters)      // [32]
{
    const int blk = blockIdx.x;
    const int tid = threadIdx.x;
    const unsigned* gh = ghist + (size_t)blk * NBIN;

    __shared__ unsigned csum[256];
    __shared__ int s_chunk;
    __shared__ unsigned s_before;

    // chunk sums: thread t covers bins [t*32, t*32+32)
    unsigned s = 0;
    #pragma unroll 8
    for (int k = 0; k < 32; ++k) s += gh[tid * 32 + k];
    csum[tid] = s;
    __syncthreads();

    // suffix over chunks ABOVE tid (LDS broadcast reads)
    unsigned suf = 0;
    for (int c = tid + 1; c < 256; ++c) suf += csum[c];
    // unique chunk where the top-PRE_K boundary falls
    if (suf < PRE_K && suf + csum[tid] >= PRE_K) { s_chunk = tid; s_before = suf; }
    __syncthreads();

    if (tid == 0) {
        int C = s_chunk;
        unsigned acc = s_before;
        int T = C * 32;
        for (int bin = C * 32 + 31; bin >= C * 32; --bin) {
            acc += gh[bin];
            if (acc >= PRE_K) { T = bin; break; }
        }
        thresh[blk]   = (unsigned)T;
        counters[blk] = 0u;       // zero collect counter for this level
    }
}

// ---------------------------------------------------------------------------
// T3: collect all candidates with key-bin >= threshold (wave-aggregated append)
// ---------------------------------------------------------------------------
__global__ __launch_bounds__(512) void collect_kernel(
    const float* __restrict__ scores0, const float* __restrict__ scores1,
    const float* __restrict__ scores2, const float* __restrict__ scores3,
    const unsigned* __restrict__ thresh,
    unsigned* __restrict__ counters,
    unsigned long long* __restrict__ cand)   // [32][CAP]
{
    const int blk = blockIdx.x / HB;
    const int hb  = blockIdx.x % HB;
    const int b   = blk >> 2;
    const int lvl = blk & 3;
    const int n   = lvl_n(lvl);
    const float* sc = lvl_scores(scores0, scores1, scores2, scores3, lvl) + (size_t)b * n;
    const unsigned T = thresh[blk];
    unsigned* cnt_ptr = counters + blk;
    unsigned long long* candp = cand + (size_t)blk * CAP;

    const int tid  = threadIdx.x;
    const int lane = tid & 63;

    for (int i = hb * 512 + tid; i < n; i += HB * 512) {
        unsigned key = f2key(sc[i]);
        bool pred = (key >> 19) >= T;
        unsigned long long act = __ballot(pred);
        if (act) {
            int leader = __ffsll((long long)act) - 1;
            unsigned base = 0;
            if (lane == leader) base = atomicAdd(cnt_ptr, (unsigned)__popcll(act));
            base = __shfl(base, leader, 64);
            if (pred) {
                unsigned pos = base + (unsigned)__popcll(act & ((1ull << lane) - 1ull));
                if (pos < CAP)
                    candp[pos] = ((unsigned long long)key << 32) | (unsigned)(~i);
            }
        }
    }
}

// ---------------------------------------------------------------------------
// T4: per-(b,lvl) bitonic sort of candidates, emit top-1000 scores + boxes
// ---------------------------------------------------------------------------
__global__ __launch_bounds__(1024) void sortemit_kernel(
    const float* __restrict__ boxes0, const float* __restrict__ boxes1,
    const float* __restrict__ boxes2, const float* __restrict__ boxes3,
    const unsigned* __restrict__ counters,
    const unsigned long long* __restrict__ cand,
    float* __restrict__ ws_scores,   // [32][1000]
    float* __restrict__ ws_boxes)    // [32][1000][4]
{
    const int blk = blockIdx.x;
    const int b   = blk >> 2;
    const int lvl = blk & 3;
    const int n   = lvl_n(lvl);
    const float* bx = lvl_boxes(boxes0, boxes1, boxes2, boxes3, lvl) + (size_t)b * n * 4;
    const unsigned long long* candp = cand + (size_t)blk * CAP;

    __shared__ unsigned long long arr[CAP];
    const int tid = threadIdx.x;
    unsigned cnt = counters[blk]; if (cnt > CAP) cnt = CAP;

    for (int i = tid; i < CAP; i += 1024)
        arr[i] = (i < (int)cnt) ? candp[i] : 0ull;
    __syncthreads();

    for (unsigned kk = 2; kk <= CAP; kk <<= 1) {
        for (unsigned j = kk >> 1; j > 0; j >>= 1) {
            for (unsigned i = tid; i < CAP; i += 1024) {
                unsigned p = i ^ j;
                if (p > i) {
                    unsigned long long a = arr[i], c = arr[p];
                    bool desc = ((i & kk) == 0);
                    if (desc ? (a < c) : (a > c)) { arr[i] = c; arr[p] = a; }
                }
            }
            __syncthreads();
        }
    }

    for (int r = tid; r < PRE_K; r += 1024) {
        unsigned long long c = arr[r];
        unsigned key = (unsigned)(c >> 32);
        int idx = (int)(~(unsigned)c);
        ws_scores[(size_t)blk * PRE_K + r] = key2f(key);
        float* dst = ws_boxes + ((size_t)blk * PRE_K + r) * 4;
        const float* src = bx + (size_t)idx * 4;
        dst[0] = src[0]; dst[1] = src[1]; dst[2] = src[2]; dst[3] = src[3];
    }
}

// ---------------------------------------------------------------------------
// Kernel 2 (fused): mask build IN LDS + chunked greedy NMS + compaction.
// One block of 1024 threads per (b,lvl). No global mask traffic at all.
//  - mask build: wave per row, __ballot word with j=w*64+lane (conflict-free
//    LDS reads, broadcast row values); lower-triangle words never written.
//  - greedy: 16 chunks of 64. Diagonal 64x64 block: one (conflicted) LDS read
//    puts all 64 diag words lane-resident; 64-step recurrence via readlane
//    (cross-lane reads independent of the chain -> chain is pure VALU).
//    Cross-chunk: lanes l>c OR-accumulate kept rows' word l, applied once.
// ---------------------------------------------------------------------------
__global__ __launch_bounds__(1024) void fused_nms_kernel(
    float* __restrict__ ws_scores,   // [32][1000] in-place
    float* __restrict__ ws_boxes)    // [32][1000][4] in-place
{
    const int blk  = blockIdx.x;
    const int tid  = threadIdx.x;
    const int lane = tid & 63;
    const int wv   = tid >> 6;       // 0..15

    __shared__ unsigned long long Mlds[1024 * NW];   // 131072 B
    __shared__ float sy1[1024], sx1[1024], sy2[1024], sx2[1024], sarea[1024];
    __shared__ float ssc[1024];
    __shared__ unsigned long long keepw[NW];
    __shared__ int wprefix[NW];

    float* scp = ws_scores + (size_t)blk * NB;
    float* bxp = ws_boxes  + (size_t)blk * NB * 4;

    // ---- stage boxes + scores into LDS ----
    for (int i = tid; i < 1024; i += 1024) {
        float y1 = 0.f, x1 = 0.f, y2 = 0.f, x2 = 0.f, s = 0.f;
        if (i < NB) {
            float4 bb = ((const float4*)bxp)[i];
            y1 = bb.x; x1 = bb.y; y2 = bb.z; x2 = bb.w;
            s = scp[i];
        }
        sy1[i] = y1; sx1[i] = x1; sy2[i] = y2; sx2[i] = x2;
        sarea[i] = (y2 - y1) * (x2 - x1);
        ssc[i] = s;
    }
    // initial keep bits: wave wv computes word wv
    {
        const int j = wv * 64 + lane;
        bool pred = (j < NB) && (scp[j] > 0.0f);
        unsigned long long bal = __ballot(pred);
        if (lane == 0) keepw[wv] = bal;
    }
    __syncthreads();

    // ---- build suppression bitmask in LDS ----
    for (int i = wv; i < NB; i += 16) {
        const float y1i = sy1[i], x1i = sx1[i], y2i = sy2[i], x2i = sx2[i], ai = sarea[i];
        for (int w = i >> 6; w < NW; ++w) {
            const int j = w * 64 + lane;
            float iy1 = fmaxf(y1i, sy1[j]);
            float ix1 = fmaxf(x1i, sx1[j]);
            float iy2 = fminf(y2i, sy2[j]);
            float ix2 = fminf(x2i, sx2[j]);
            float ih = fmaxf(iy2 - iy1, 0.0f);
            float iw = fmaxf(ix2 - ix1, 0.0f);
            float inter = ih * iw;
            float uni = ai + sarea[j] - inter;
            // exact IEEE division to match the numpy reference bit-for-bit
            bool pred = (j > i) && (j < NB) && (uni > 0.0f) && (inter / uni > 0.7f);
            unsigned long long m = __ballot(pred);
            if (lane == 0) Mlds[i * NW + w] = m;
        }
    }
    __syncthreads();

    // ---- chunked greedy pass on wave 0 ----
    if (tid < 64) {
        unsigned long long kp = (lane < NW) ? keepw[lane] : 0ull;
        for (int c = 0; c < NW; ++c) {
            unsigned long long w = __shfl(kp, c, 64);
            // lane i holds diag word of row c*64+i (one conflicted LDS read)
            unsigned long long dw = Mlds[(size_t)(c * 64 + lane) * NW + c];
            unsigned dlo = (unsigned)dw, dhi = (unsigned)(dw >> 32);
            #pragma unroll
            for (int i = 0; i < 64; ++i) {
                unsigned long long di =
                    ((unsigned long long)(unsigned)__builtin_amdgcn_readlane((int)dhi, i) << 32) |
                    (unsigned)__builtin_amdgcn_readlane((int)dlo, i);
                if ((w >> i) & 1ull) w &= ~di;
            }
            if (lane == c) kp = w;
            // cross-chunk apply: lanes l>c accumulate kept rows' word l
            unsigned long long acc = 0ull;
            if (lane > c && lane < NW) {
                const unsigned long long* col = &Mlds[(size_t)(c * 64) * NW + lane];
                #pragma unroll 16
                for (int i = 0; i < 64; ++i) {
                    unsigned long long m = col[(size_t)i * NW];
                    if ((w >> i) & 1ull) acc |= m;
                }
            }
            kp &= ~acc;
        }
        if (lane < NW) keepw[lane] = kp;
    }
    __syncthreads();
    if (tid == 0) {
        int acc = 0;
        for (int w = 0; w < NW; ++w) { wprefix[w] = acc; acc += __popcll(keepw[w]); }
    }
    __syncthreads();

    // ---- zero-fill then stable scatter of survivors (from LDS copies) ----
    for (int i = tid; i < NB; i += 1024) scp[i] = 0.0f;
    for (int i = tid; i < NB * 4; i += 1024) bxp[i] = 0.0f;
    __syncthreads();
    for (int i = tid; i < NB; i += 1024) {
        const int w = i >> 6;
        const unsigned long long kw = keepw[w];
        if ((kw >> (i & 63)) & 1ull) {
            int rank = wprefix[w] + __popcll(kw & ((1ull << (i & 63)) - 1ull));
            scp[rank] = ssc[i];
            float* dst = bxp + (size_t)rank * 4;
            dst[0] = sy1[i]; dst[1] = sx1[i]; dst[2] = sy2[i]; dst[3] = sx2[i];
        }
    }
}

// ---------------------------------------------------------------------------
// Kernel 3: per-batch final top-1000 over 4000 concatenated entries
// ---------------------------------------------------------------------------
__global__ __launch_bounds__(1024) void final_topk_kernel(
    const float* __restrict__ ws_scores,  // [8][4][1000] == [8][4000]
    const float* __restrict__ ws_boxes,   // [8][4000][4]
    float* __restrict__ out)              // rois (8*1000*4) then scores (8*1000)
{
    const int b = blockIdx.x;
    const int tid = threadIdx.x;
    __shared__ unsigned long long arr[TOTP];

    for (int i = tid; i < TOTP; i += 1024) {
        unsigned long long c = 0ull;
        if (i < TOT) {
            unsigned u = f2key(ws_scores[(size_t)b * TOT + i]);
            c = ((unsigned long long)u << 32) | (unsigned)(~i);
        }
        arr[i] = c;
    }
    __syncthreads();

    for (unsigned kk = 2; kk <= TOTP; kk <<= 1) {
        for (unsigned j = kk >> 1; j > 0; j >>= 1) {
            for (unsigned i = tid; i < TOTP; i += 1024) {
                unsigned p = i ^ j;
                if (p > i) {
                    unsigned long long a = arr[i], c = arr[p];
                    bool desc = ((i & kk) == 0);
                    if (desc ? (a < c) : (a > c)) { arr[i] = c; arr[p] = a; }
                }
            }
            __syncthreads();
        }
    }

    float* out_rois   = out;            // (8,1000,4)
    float* out_scores = out + 32000;    // (8,1000)
    for (int r = tid; r < 1000; r += 1024) {
        unsigned long long c = arr[r];
        int pos = (int)(~(unsigned)c);
        unsigned key = (unsigned)(c >> 32);
        out_scores[(size_t)b * 1000 + r] = key2f(key);
        const float* src = ws_boxes + ((size_t)b * TOT + pos) * 4;
        float* dst = out_rois + ((size_t)b * 1000 + r) * 4;
        dst[0] = src[0]; dst[1] = src[1]; dst[2] = src[2]; dst[3] = src[3];
    }
}

// ---------------------------------------------------------------------------
extern "C" void kernel_launch(void* const* d_in, const int* in_sizes, int n_in,
                              void* d_out, int out_size, void* d_ws, size_t ws_size,
                              hipStream_t stream) {
    // setup_inputs() dict order: boxes_p2, scores_p2, boxes_p3, scores_p3,
    //                            boxes_p4, scores_p4, boxes_p5, scores_p5
    const float* boxes0  = (const float*)d_in[0];
    const float* scores0 = (const float*)d_in[1];
    const float* boxes1  = (const float*)d_in[2];
    const float* scores1 = (const float*)d_in[3];
    const float* boxes2  = (const float*)d_in[4];
    const float* scores2 = (const float*)d_in[5];
    const float* boxes3  = (const float*)d_in[6];
    const float* scores3 = (const float*)d_in[7];
    float* out = (float*)d_out;

    // ws carve: scores [32*1000] | boxes [32*1000*4] | topk scratch
    char* base = (char*)d_ws;
    float* ws_scores = (float*)base;                               // 128000 B
    float* ws_boxes  = (float*)(base + 128000);                    // 512000 B
    unsigned long long* cand = (unsigned long long*)(base + 640000);     // 524288 B
    unsigned* ghist    = (unsigned*)(base + 1164288);              // 1048576 B
    unsigned* counters = (unsigned*)(base + 2212864);              // 128 B
    unsigned* thresh   = (unsigned*)(base + 2212992);              // 128 B

    init_kernel<<<128, 512, 0, stream>>>(ghist);
    hist_kernel<<<BATCH * NLVL * HB, 512, 0, stream>>>(
        scores0, scores1, scores2, scores3, ghist);
    select_kernel<<<BATCH * NLVL, 256, 0, stream>>>(ghist, thresh, counters);
    collect_kernel<<<BATCH * NLVL * HB, 512, 0, stream>>>(
        scores0, scores1, scores2, scores3, thresh, counters, cand);
    sortemit_kernel<<<BATCH * NLVL, 1024, 0, stream>>>(
        boxes0, boxes1, boxes2, boxes3, counters, cand, ws_scores, ws_boxes);
    fused_nms_kernel<<<BATCH * NLVL, 1024, 0, stream>>>(ws_scores, ws_boxes);
    final_topk_kernel<<<BATCH, 1024, 0, stream>>>(ws_scores, ws_boxes, out);
}

// Round 6
// 246.787 us; speedup vs baseline: 1.8294x; 1.8294x over previous
//
#include <hip/hip_runtime.h>

#define PRE_K 1000
#define CAP   2048      // candidate buffer per level (>= PRE_K + max bin, pow2)
#define NBIN  8192      // 13-bit key-prefix histogram bins
#define NB    1000      // boxes per level after pre-NMS topk
#define NW    16        // 64-bit words covering NB bits (16*64 = 1024)
#define TOT   4000      // concatenated entries per batch
#define TOTP  4096      // padded pow2 for bitonic
#define NLVL  4
#define BATCH 8
#define HB    8         // blocks per (b,lvl) for hist/collect
#define MB    8         // blocks per (b,lvl) for mask build

__device__ __forceinline__ unsigned f2key(float f) {
    unsigned u = __float_as_uint(f);
    return (u & 0x80000000u) ? ~u : (u | 0x80000000u);   // monotonic ascending
}
__device__ __forceinline__ float key2f(unsigned k) {
    unsigned u = (k & 0x80000000u) ? (k & 0x7FFFFFFFu) : ~k;
    return __uint_as_float(u);
}
__device__ __forceinline__ const float* lvl_scores(
    const float* s0, const float* s1, const float* s2, const float* s3, int lvl) {
    switch (lvl) { case 0: return s0; case 1: return s1; case 2: return s2; default: return s3; }
}
__device__ __forceinline__ const float* lvl_boxes(
    const float* b0, const float* b1, const float* b2, const float* b3, int lvl) {
    switch (lvl) { case 0: return b0; case 1: return b1; case 2: return b2; default: return b3; }
}
__device__ __forceinline__ int lvl_n(int lvl) {
    const int sizes[4] = {196608, 49152, 12288, 3072};
    return sizes[lvl];
}

// ---------------------------------------------------------------------------
// T0: zero global histograms
// ---------------------------------------------------------------------------
__global__ __launch_bounds__(512) void init_kernel(unsigned* __restrict__ ghist) {
    const int stride = gridDim.x * 512;
    for (int i = blockIdx.x * 512 + threadIdx.x; i < 32 * NBIN; i += stride)
        ghist[i] = 0u;
}

// ---------------------------------------------------------------------------
// T1: per-(b,lvl) 13-bit-prefix histogram. float4 loads; 2 bank-replicas to
// halve hot-bin LDS atomic serialization (N(0,1) scores concentrate bins).
// ---------------------------------------------------------------------------
__global__ __launch_bounds__(512) void hist_kernel(
    const float* __restrict__ scores0, const float* __restrict__ scores1,
    const float* __restrict__ scores2, const float* __restrict__ scores3,
    unsigned* __restrict__ ghist)      // [32][NBIN]
{
    const int blk = blockIdx.x / HB;   // b*4 + lvl
    const int hb  = blockIdx.x % HB;
    const int b   = blk >> 2;
    const int lvl = blk & 3;
    const int n   = lvl_n(lvl);
    const float* sc = lvl_scores(scores0, scores1, scores2, scores3, lvl) + (size_t)b * n;

    __shared__ unsigned lhist[2][NBIN];   // 64 KB
    const int tid = threadIdx.x;
    const int rep = (tid >> 6) & 1;       // wave-uniform replica
    for (int i = tid; i < 2 * NBIN; i += 512) (&lhist[0][0])[i] = 0u;
    __syncthreads();

    const float4* sc4 = (const float4*)sc;
    const int n4 = n >> 2;                // all level sizes divisible by 4
    for (int i = hb * 512 + tid; i < n4; i += HB * 512) {
        float4 v = sc4[i];
        atomicAdd(&lhist[rep][f2key(v.x) >> 19], 1u);
        atomicAdd(&lhist[rep][f2key(v.y) >> 19], 1u);
        atomicAdd(&lhist[rep][f2key(v.z) >> 19], 1u);
        atomicAdd(&lhist[rep][f2key(v.w) >> 19], 1u);
    }
    __syncthreads();

    unsigned* gh = ghist + (size_t)blk * NBIN;
    for (int i = tid; i < NBIN; i += 512) {
        unsigned v = lhist[0][i] + lhist[1][i];
        if (v) atomicAdd(&gh[i], v);
    }
}

// ---------------------------------------------------------------------------
// T2: per-(b,lvl) threshold-bin selection (top-PRE_K boundary); zero counters
// ---------------------------------------------------------------------------
__global__ __launch_bounds__(256) void select_kernel(
    const unsigned* __restrict__ ghist,   // [32][NBIN]
    unsigned* __restrict__ thresh,        // [32]
    unsigned* __restrict__ counters)      // [32]
{
    const int blk = blockIdx.x;
    const int tid = threadIdx.x;
    const unsigned* gh = ghist + (size_t)blk * NBIN;

    __shared__ unsigned csum[256];
    __shared__ int s_chunk;
    __shared__ unsigned s_before;

    // chunk sums: thread t covers bins [t*32, t*32+32)
    unsigned s = 0;
    #pragma unroll 8
    for (int k = 0; k < 32; ++k) s += gh[tid * 32 + k];
    csum[tid] = s;
    __syncthreads();

    // suffix over chunks ABOVE tid (LDS broadcast reads)
    unsigned suf = 0;
    for (int c = tid + 1; c < 256; ++c) suf += csum[c];
    // unique chunk where the top-PRE_K boundary falls
    if (suf < PRE_K && suf + csum[tid] >= PRE_K) { s_chunk = tid; s_before = suf; }
    __syncthreads();

    if (tid == 0) {
        int C = s_chunk;
        unsigned acc = s_before;
        int T = C * 32;
        for (int bin = C * 32 + 31; bin >= C * 32; --bin) {
            acc += gh[bin];
            if (acc >= PRE_K) { T = bin; break; }
        }
        thresh[blk]   = (unsigned)T;
        counters[blk] = 0u;       // zero collect counter for this level
    }
}

// ---------------------------------------------------------------------------
// T3: collect candidates with key-bin >= threshold. LDS-buffered per block,
// ONE global atomic per block (order across blocks irrelevant: sorted later,
// stable tie-break lives in the composite key's ~idx).
// ---------------------------------------------------------------------------
__global__ __launch_bounds__(512) void collect_kernel(
    const float* __restrict__ scores0, const float* __restrict__ scores1,
    const float* __restrict__ scores2, const float* __restrict__ scores3,
    const unsigned* __restrict__ thresh,
    unsigned* __restrict__ counters,
    unsigned long long* __restrict__ cand)   // [32][CAP]
{
    const int blk = blockIdx.x / HB;
    const int hb  = blockIdx.x % HB;
    const int b   = blk >> 2;
    const int lvl = blk & 3;
    const int n   = lvl_n(lvl);
    const float* sc = lvl_scores(scores0, scores1, scores2, scores3, lvl) + (size_t)b * n;
    const unsigned T = thresh[blk];
    unsigned long long* candp = cand + (size_t)blk * CAP;

    __shared__ unsigned long long cbuf[CAP];
    __shared__ unsigned ccnt, cbase;

    const int tid  = threadIdx.x;
    const int lane = tid & 63;
    if (tid == 0) ccnt = 0;
    __syncthreads();

    for (int i = hb * 512 + tid; i < n; i += HB * 512) {
        unsigned key = f2key(sc[i]);
        bool pred = (key >> 19) >= T;
        unsigned long long act = __ballot(pred);
        if (act) {
            int leader = __ffsll((long long)act) - 1;
            unsigned base = 0;
            if (lane == leader) base = atomicAdd(&ccnt, (unsigned)__popcll(act));
            base = __shfl(base, leader, 64);
            if (pred) {
                unsigned pos = base + (unsigned)__popcll(act & ((1ull << lane) - 1ull));
                if (pos < CAP)
                    cbuf[pos] = ((unsigned long long)key << 32) | (unsigned)(~i);
            }
        }
    }
    __syncthreads();
    unsigned cnt = ccnt; if (cnt > CAP) cnt = CAP;
    if (tid == 0) cbase = atomicAdd(&counters[blk], cnt);
    __syncthreads();
    const unsigned gb = cbase;
    for (unsigned i = tid; i < cnt; i += 512) {
        unsigned p = gb + i;
        if (p < CAP) candp[p] = cbuf[i];
    }
}

// ---------------------------------------------------------------------------
// T4: per-(b,lvl) bitonic sort of candidates, emit top-1000 scores + boxes
// ---------------------------------------------------------------------------
__global__ __launch_bounds__(1024) void sortemit_kernel(
    const float* __restrict__ boxes0, const float* __restrict__ boxes1,
    const float* __restrict__ boxes2, const float* __restrict__ boxes3,
    const unsigned* __restrict__ counters,
    const unsigned long long* __restrict__ cand,
    float* __restrict__ ws_scores,   // [32][1000]
    float* __restrict__ ws_boxes)    // [32][1000][4]
{
    const int blk = blockIdx.x;
    const int b   = blk >> 2;
    const int lvl = blk & 3;
    const int n   = lvl_n(lvl);
    const float* bx = lvl_boxes(boxes0, boxes1, boxes2, boxes3, lvl) + (size_t)b * n * 4;
    const unsigned long long* candp = cand + (size_t)blk * CAP;

    __shared__ unsigned long long arr[CAP];
    const int tid = threadIdx.x;
    unsigned cnt = counters[blk]; if (cnt > CAP) cnt = CAP;

    for (int i = tid; i < CAP; i += 1024)
        arr[i] = (i < (int)cnt) ? candp[i] : 0ull;
    __syncthreads();

    for (unsigned kk = 2; kk <= CAP; kk <<= 1) {
        for (unsigned j = kk >> 1; j > 0; j >>= 1) {
            for (unsigned i = tid; i < CAP; i += 1024) {
                unsigned p = i ^ j;
                if (p > i) {
                    unsigned long long a = arr[i], c = arr[p];
                    bool desc = ((i & kk) == 0);
                    if (desc ? (a < c) : (a > c)) { arr[i] = c; arr[p] = a; }
                }
            }
            __syncthreads();
        }
    }

    for (int r = tid; r < PRE_K; r += 1024) {
        unsigned long long c = arr[r];
        unsigned key = (unsigned)(c >> 32);
        int idx = (int)(~(unsigned)c);
        ws_scores[(size_t)blk * PRE_K + r] = key2f(key);
        float* dst = ws_boxes + ((size_t)blk * PRE_K + r) * 4;
        const float* src = bx + (size_t)idx * 4;
        dst[0] = src[0]; dst[1] = src[1]; dst[2] = src[2]; dst[3] = src[3];
    }
}

// ---------------------------------------------------------------------------
// Kernel 2a: parallel mask build, 8 blocks/level. Each wave owns 4 words
// (balanced sets {v,7-v,8+v,15-v}); lane's j-box register-cached -> only ONE
// broadcast float4 LDS read per row. Exact IEEE div runs only for words whose
// band-ballot (inter > 0.69*uni) is nonzero: inter<=fl(0.69*uni) proves
// fl(inter/uni) < 0.7f, so selection is bit-identical to always-divide.
// ---------------------------------------------------------------------------
__global__ __launch_bounds__(256) void mask_kernel(
    const float* __restrict__ ws_boxes,
    unsigned long long* __restrict__ ws_mask)   // [32][1000][16]
{
    const int blk  = blockIdx.x >> 3;    // (b,lvl)
    const int mb   = blockIdx.x & (MB - 1);
    const int tid  = threadIdx.x;
    const int lane = tid & 63;
    const int v    = tid >> 6;           // wave 0..3

    __shared__ float4 sbox[1024];

    const float4* bxp = (const float4*)(ws_boxes + (size_t)blk * NB * 4);
    for (int i = tid; i < 1024; i += 256)
        sbox[i] = (i < NB) ? bxp[i] : make_float4(0.f, 0.f, 0.f, 0.f);
    __syncthreads();

    unsigned long long* maskp = ws_mask + (size_t)blk * NB * NW;
    const int wset[4] = {v, 7 - v, 8 + v, 15 - v};
    #pragma unroll
    for (int s = 0; s < 4; ++s) {
        const int w = wset[s];
        const int j = w * 64 + lane;
        const float4 jb = sbox[j];
        const float aj = (jb.z - jb.x) * (jb.w - jb.y);
        const int rmax = min((w + 1) * 64, NB);
        for (int i = mb; i < rmax; i += MB) {
            float4 rb = sbox[i];                    // broadcast read
            float ai = (rb.z - rb.x) * (rb.w - rb.y);
            float iy1 = fmaxf(rb.x, jb.x);
            float ix1 = fmaxf(rb.y, jb.y);
            float iy2 = fminf(rb.z, jb.z);
            float ix2 = fminf(rb.w, jb.w);
            float ih = fmaxf(iy2 - iy1, 0.0f);
            float iw = fmaxf(ix2 - ix1, 0.0f);
            float inter = ih * iw;
            float uni = ai + aj - inter;
            bool amb = inter > 0.69f * uni;         // conservative band
            bool pred = false;
            if (__ballot(amb))                      // rare: exact IEEE div
                pred = (uni > 0.0f) && (inter / uni > 0.7f);
            pred = pred && (j > i);
            unsigned long long m = __ballot(pred);
            if (lane == 0) maskp[i * NW + w] = m;
        }
    }
}

// ---------------------------------------------------------------------------
// Kernel 2b: greedy NMS. Mask staged global->LDS with 1024 threads (8
// independent b128 loads/thread, latency pipelined). Serial pass on wave 0:
// readlane diagonal recurrence + branchless bit-masked applies (loads hoisted
// -- the R4 lesson: conditional-expression LDS loads compile branchy/serial).
// ---------------------------------------------------------------------------
__global__ __launch_bounds__(1024) void greedy_kernel(
    float* __restrict__ ws_scores,   // [32][1000] in-place
    float* __restrict__ ws_boxes,    // [32][1000][4] in-place
    const unsigned long long* __restrict__ ws_mask)
{
    const int blk  = blockIdx.x;
    const int tid  = threadIdx.x;
    const int lane = tid & 63;
    const int wv   = tid >> 6;       // 0..15

    __shared__ unsigned long long Mlds[1024 * NW];   // 131072 B (rows>=1000: garbage, never applied)
    __shared__ float4 sbox[NB];                      // 16000 B
    __shared__ float  ssc[NB];                       //  4000 B
    __shared__ unsigned long long keepw[NW];
    __shared__ int wprefix[NW];

    float* scp = ws_scores + (size_t)blk * NB;
    float* bxp = ws_boxes  + (size_t)blk * NB * 4;
    const unsigned long long* mrows = ws_mask + (size_t)blk * NB * NW;

    // ---- stage mask (16B vectors) + boxes + scores into LDS ----
    {
        const ulonglong2* src = (const ulonglong2*)mrows;
        ulonglong2* dst = (ulonglong2*)Mlds;
        for (int i = tid; i < NB * NW / 2; i += 1024) dst[i] = src[i];
    }
    for (int i = tid; i < NB; i += 1024) {
        sbox[i] = ((const float4*)bxp)[i];
        ssc[i]  = scp[i];
    }
    // initial keep bits: wave wv computes word wv
    {
        const int j = wv * 64 + lane;
        bool pred = (j < NB) && (scp[j] > 0.0f);
        unsigned long long bal = __ballot(pred);
        if (lane == 0) keepw[wv] = bal;
    }
    __syncthreads();

    // ---- chunked greedy pass on wave 0 ----
    if (tid < 64) {
        unsigned long long kp = (lane < NW) ? keepw[lane] : 0ull;
        for (int c = 0; c < NW; ++c) {
            unsigned long long w = __shfl(kp, c, 64);
            // lane i holds diag word of row c*64+i (one conflicted LDS read)
            unsigned long long dw = Mlds[(size_t)(c * 64 + lane) * NW + c];
            unsigned dlo = (unsigned)dw, dhi = (unsigned)(dw >> 32);
            #pragma unroll
            for (int i = 0; i < 64; ++i) {
                unsigned long long di =
                    ((unsigned long long)(unsigned)__builtin_amdgcn_readlane((int)dhi, i) << 32) |
                    (unsigned)__builtin_amdgcn_readlane((int)dlo, i);
                unsigned long long bit = (w >> i) & 1ull;
                w &= ~(di & (0ull - bit));           // branchless apply
            }
            if (lane == c) kp = w;
            // cross-chunk apply: lanes l>c accumulate kept rows' word l
            unsigned long long acc = 0ull;
            if (lane > c && lane < NW) {
                const unsigned long long* col = &Mlds[(size_t)(c * 64) * NW + lane];
                #pragma unroll 16
                for (int i = 0; i < 64; ++i) {
                    unsigned long long m = col[(size_t)i * NW];   // hoisted load
                    unsigned long long bit = (w >> i) & 1ull;
                    acc |= m & (0ull - bit);
                }
            }
            kp &= ~acc;
        }
        if (lane < NW) keepw[lane] = kp;
    }
    __syncthreads();
    if (tid == 0) {
        int acc = 0;
        for (int w = 0; w < NW; ++w) { wprefix[w] = acc; acc += __popcll(keepw[w]); }
    }
    __syncthreads();

    // ---- zero-fill then stable scatter of survivors (from LDS copies) ----
    for (int i = tid; i < NB; i += 1024) scp[i] = 0.0f;
    for (int i = tid; i < NB * 4; i += 1024) bxp[i] = 0.0f;
    __syncthreads();
    for (int i = tid; i < NB; i += 1024) {
        const int w = i >> 6;
        const unsigned long long kw = keepw[w];
        if ((kw >> (i & 63)) & 1ull) {
            int rank = wprefix[w] + __popcll(kw & ((1ull << (i & 63)) - 1ull));
            scp[rank] = ssc[i];
            float4 bb = sbox[i];
            float* dst = bxp + (size_t)rank * 4;
            dst[0] = bb.x; dst[1] = bb.y; dst[2] = bb.z; dst[3] = bb.w;
        }
    }
}

// ---------------------------------------------------------------------------
// Kernel 3: per-batch final top-1000 over 4000 concatenated entries
// ---------------------------------------------------------------------------
__global__ __launch_bounds__(1024) void final_topk_kernel(
    const float* __restrict__ ws_scores,  // [8][4][1000] == [8][4000]
    const float* __restrict__ ws_boxes,   // [8][4000][4]
    float* __restrict__ out)              // rois (8*1000*4) then scores (8*1000)
{
    const int b = blockIdx.x;
    const int tid = threadIdx.x;
    __shared__ unsigned long long arr[TOTP];

    for (int i = tid; i < TOTP; i += 1024) {
        unsigned long long c = 0ull;
        if (i < TOT) {
            unsigned u = f2key(ws_scores[(size_t)b * TOT + i]);
            c = ((unsigned long long)u << 32) | (unsigned)(~i);
        }
        arr[i] = c;
    }
    __syncthreads();

    for (unsigned kk = 2; kk <= TOTP; kk <<= 1) {
        for (unsigned j = kk >> 1; j > 0; j >>= 1) {
            for (unsigned i = tid; i < TOTP; i += 1024) {
                unsigned p = i ^ j;
                if (p > i) {
                    unsigned long long a = arr[i], c = arr[p];
                    bool desc = ((i & kk) == 0);
                    if (desc ? (a < c) : (a > c)) { arr[i] = c; arr[p] = a; }
                }
            }
            __syncthreads();
        }
    }

    float* out_rois   = out;            // (8,1000,4)
    float* out_scores = out + 32000;    // (8,1000)
    for (int r = tid; r < 1000; r += 1024) {
        unsigned long long c = arr[r];
        int pos = (int)(~(unsigned)c);
        unsigned key = (unsigned)(c >> 32);
        out_scores[(size_t)b * 1000 + r] = key2f(key);
        const float* src = ws_boxes + ((size_t)b * TOT + pos) * 4;
        float* dst = out_rois + ((size_t)b * 1000 + r) * 4;
        dst[0] = src[0]; dst[1] = src[1]; dst[2] = src[2]; dst[3] = src[3];
    }
}

// ---------------------------------------------------------------------------
extern "C" void kernel_launch(void* const* d_in, const int* in_sizes, int n_in,
                              void* d_out, int out_size, void* d_ws, size_t ws_size,
                              hipStream_t stream) {
    // setup_inputs() dict order: boxes_p2, scores_p2, boxes_p3, scores_p3,
    //                            boxes_p4, scores_p4, boxes_p5, scores_p5
    const float* boxes0  = (const float*)d_in[0];
    const float* scores0 = (const float*)d_in[1];
    const float* boxes1  = (const float*)d_in[2];
    const float* scores1 = (const float*)d_in[3];
    const float* boxes2  = (const float*)d_in[4];
    const float* scores2 = (const float*)d_in[5];
    const float* boxes3  = (const float*)d_in[6];
    const float* scores3 = (const float*)d_in[7];
    float* out = (float*)d_out;

    // ws carve: scores [32*1000] | boxes [32*1000*4] | mask [32*1000*16 u64]
    // topk scratch (cand/ghist/counters/thresh) OVERLAYS the mask region:
    // all of it is dead before mask_kernel writes.
    char* base = (char*)d_ws;
    float* ws_scores = (float*)base;                                     // 128000 B
    float* ws_boxes  = (float*)(base + 128000);                          // 512000 B
    unsigned long long* ws_mask = (unsigned long long*)(base + 640000);  // 4096000 B
    // overlay inside mask region:
    unsigned long long* cand = (unsigned long long*)(base + 640000);     // 524288 B
    unsigned* ghist    = (unsigned*)(base + 1164288);                    // 1048576 B
    unsigned* counters = (unsigned*)(base + 2212864);                    // 128 B
    unsigned* thresh   = (unsigned*)(base + 2212992);                    // 128 B

    init_kernel<<<128, 512, 0, stream>>>(ghist);
    hist_kernel<<<BATCH * NLVL * HB, 512, 0, stream>>>(
        scores0, scores1, scores2, scores3, ghist);
    select_kernel<<<BATCH * NLVL, 256, 0, stream>>>(ghist, thresh, counters);
    collect_kernel<<<BATCH * NLVL * HB, 512, 0, stream>>>(
        scores0, scores1, scores2, scores3, thresh, counters, cand);
    sortemit_kernel<<<BATCH * NLVL, 1024, 0, stream>>>(
        boxes0, boxes1, boxes2, boxes3, counters, cand, ws_scores, ws_boxes);
    mask_kernel<<<BATCH * NLVL * MB, 256, 0, stream>>>(ws_boxes, ws_mask);
    greedy_kernel<<<BATCH * NLVL, 1024, 0, stream>>>(ws_scores, ws_boxes, ws_mask);
    final_topk_kernel<<<BATCH, 1024, 0, stream>>>(ws_scores, ws_boxes, out);
}

// Round 7
// 189.295 us; speedup vs baseline: 2.3851x; 1.3037x over previous
//
#include <hip/hip_runtime.h>

#define PRE_K 1000
#define CAP   2048      // candidate buffer per level (>= PRE_K + max bin, pow2)
#define NBIN  8192      // 13-bit key-prefix histogram bins
#define NB    1000      // boxes per level after pre-NMS topk
#define NW    16        // 64-bit words covering NB bits (16*64 = 1024)
#define TOT   4000      // concatenated entries per batch
#define NLVL  4
#define BATCH 8
#define HB    8         // blocks per (b,lvl) for hist/collect
#define MB    8         // blocks per (b,lvl) for mask build

__device__ __forceinline__ unsigned f2key(float f) {
    unsigned u = __float_as_uint(f);
    return (u & 0x80000000u) ? ~u : (u | 0x80000000u);   // monotonic ascending
}
__device__ __forceinline__ float key2f(unsigned k) {
    unsigned u = (k & 0x80000000u) ? (k & 0x7FFFFFFFu) : ~k;
    return __uint_as_float(u);
}
__device__ __forceinline__ const float* lvl_scores(
    const float* s0, const float* s1, const float* s2, const float* s3, int lvl) {
    switch (lvl) { case 0: return s0; case 1: return s1; case 2: return s2; default: return s3; }
}
__device__ __forceinline__ const float* lvl_boxes(
    const float* b0, const float* b1, const float* b2, const float* b3, int lvl) {
    switch (lvl) { case 0: return b0; case 1: return b1; case 2: return b2; default: return b3; }
}
__device__ __forceinline__ int lvl_n(int lvl) {
    const int sizes[4] = {196608, 49152, 12288, 3072};
    return sizes[lvl];
}

// ---------------------------------------------------------------------------
// T0: zero global histograms
// ---------------------------------------------------------------------------
__global__ __launch_bounds__(512) void init_kernel(unsigned* __restrict__ ghist) {
    const int stride = gridDim.x * 512;
    for (int i = blockIdx.x * 512 + threadIdx.x; i < 32 * NBIN; i += stride)
        ghist[i] = 0u;
}

// ---------------------------------------------------------------------------
// T1: per-(b,lvl) 13-bit-prefix histogram. float4 loads; 2 bank-replicas to
// halve hot-bin LDS atomic serialization (N(0,1) scores concentrate bins).
// ---------------------------------------------------------------------------
__global__ __launch_bounds__(512) void hist_kernel(
    const float* __restrict__ scores0, const float* __restrict__ scores1,
    const float* __restrict__ scores2, const float* __restrict__ scores3,
    unsigned* __restrict__ ghist)      // [32][NBIN]
{
    const int blk = blockIdx.x / HB;   // b*4 + lvl
    const int hb  = blockIdx.x % HB;
    const int b   = blk >> 2;
    const int lvl = blk & 3;
    const int n   = lvl_n(lvl);
    const float* sc = lvl_scores(scores0, scores1, scores2, scores3, lvl) + (size_t)b * n;

    __shared__ unsigned lhist[2][NBIN];   // 64 KB
    const int tid = threadIdx.x;
    const int rep = (tid >> 6) & 1;       // wave-uniform replica
    for (int i = tid; i < 2 * NBIN; i += 512) (&lhist[0][0])[i] = 0u;
    __syncthreads();

    const float4* sc4 = (const float4*)sc;
    const int n4 = n >> 2;                // all level sizes divisible by 4
    for (int i = hb * 512 + tid; i < n4; i += HB * 512) {
        float4 v = sc4[i];
        atomicAdd(&lhist[rep][f2key(v.x) >> 19], 1u);
        atomicAdd(&lhist[rep][f2key(v.y) >> 19], 1u);
        atomicAdd(&lhist[rep][f2key(v.z) >> 19], 1u);
        atomicAdd(&lhist[rep][f2key(v.w) >> 19], 1u);
    }
    __syncthreads();

    unsigned* gh = ghist + (size_t)blk * NBIN;
    for (int i = tid; i < NBIN; i += 512) {
        unsigned v = lhist[0][i] + lhist[1][i];
        if (v) atomicAdd(&gh[i], v);
    }
}

// ---------------------------------------------------------------------------
// T2: per-(b,lvl) threshold-bin selection (top-PRE_K boundary); zero counters
// ---------------------------------------------------------------------------
__global__ __launch_bounds__(256) void select_kernel(
    const unsigned* __restrict__ ghist,   // [32][NBIN]
    unsigned* __restrict__ thresh,        // [32]
    unsigned* __restrict__ counters)      // [32]
{
    const int blk = blockIdx.x;
    const int tid = threadIdx.x;
    const unsigned* gh = ghist + (size_t)blk * NBIN;

    __shared__ unsigned csum[256];
    __shared__ int s_chunk;
    __shared__ unsigned s_before;

    // chunk sums: thread t covers bins [t*32, t*32+32)
    unsigned s = 0;
    #pragma unroll 8
    for (int k = 0; k < 32; ++k) s += gh[tid * 32 + k];
    csum[tid] = s;
    __syncthreads();

    // suffix over chunks ABOVE tid (LDS broadcast reads)
    unsigned suf = 0;
    for (int c = tid + 1; c < 256; ++c) suf += csum[c];
    // unique chunk where the top-PRE_K boundary falls
    if (suf < PRE_K && suf + csum[tid] >= PRE_K) { s_chunk = tid; s_before = suf; }
    __syncthreads();

    if (tid == 0) {
        int C = s_chunk;
        unsigned acc = s_before;
        int T = C * 32;
        for (int bin = C * 32 + 31; bin >= C * 32; --bin) {
            acc += gh[bin];
            if (acc >= PRE_K) { T = bin; break; }
        }
        thresh[blk]   = (unsigned)T;
        counters[blk] = 0u;       // zero collect counter for this level
    }
}

// ---------------------------------------------------------------------------
// T3: collect candidates with key-bin >= threshold. LDS-buffered per block,
// ONE global atomic per block (order across blocks irrelevant: sorted later,
// stable tie-break lives in the composite key's ~idx).
// ---------------------------------------------------------------------------
__global__ __launch_bounds__(512) void collect_kernel(
    const float* __restrict__ scores0, const float* __restrict__ scores1,
    const float* __restrict__ scores2, const float* __restrict__ scores3,
    const unsigned* __restrict__ thresh,
    unsigned* __restrict__ counters,
    unsigned long long* __restrict__ cand)   // [32][CAP]
{
    const int blk = blockIdx.x / HB;
    const int hb  = blockIdx.x % HB;
    const int b   = blk >> 2;
    const int lvl = blk & 3;
    const int n   = lvl_n(lvl);
    const float* sc = lvl_scores(scores0, scores1, scores2, scores3, lvl) + (size_t)b * n;
    const unsigned T = thresh[blk];
    unsigned long long* candp = cand + (size_t)blk * CAP;

    __shared__ unsigned long long cbuf[CAP];
    __shared__ unsigned ccnt, cbase;

    const int tid  = threadIdx.x;
    const int lane = tid & 63;
    if (tid == 0) ccnt = 0;
    __syncthreads();

    for (int i = hb * 512 + tid; i < n; i += HB * 512) {
        unsigned key = f2key(sc[i]);
        bool pred = (key >> 19) >= T;
        unsigned long long act = __ballot(pred);
        if (act) {
            int leader = __ffsll((long long)act) - 1;
            unsigned base = 0;
            if (lane == leader) base = atomicAdd(&ccnt, (unsigned)__popcll(act));
            base = __shfl(base, leader, 64);
            if (pred) {
                unsigned pos = base + (unsigned)__popcll(act & ((1ull << lane) - 1ull));
                if (pos < CAP)
                    cbuf[pos] = ((unsigned long long)key << 32) | (unsigned)(~i);
            }
        }
    }
    __syncthreads();
    unsigned cnt = ccnt; if (cnt > CAP) cnt = CAP;
    if (tid == 0) cbase = atomicAdd(&counters[blk], cnt);
    __syncthreads();
    const unsigned gb = cbase;
    for (unsigned i = tid; i < cnt; i += 512) {
        unsigned p = gb + i;
        if (p < CAP) candp[p] = cbuf[i];
    }
}

// ---------------------------------------------------------------------------
// T4: per-(b,lvl) bitonic sort of candidates, emit top-1000 scores + boxes
// ---------------------------------------------------------------------------
__global__ __launch_bounds__(1024) void sortemit_kernel(
    const float* __restrict__ boxes0, const float* __restrict__ boxes1,
    const float* __restrict__ boxes2, const float* __restrict__ boxes3,
    const unsigned* __restrict__ counters,
    const unsigned long long* __restrict__ cand,
    float* __restrict__ ws_scores,   // [32][1000]
    float* __restrict__ ws_boxes)    // [32][1000][4]
{
    const int blk = blockIdx.x;
    const int b   = blk >> 2;
    const int lvl = blk & 3;
    const int n   = lvl_n(lvl);
    const float* bx = lvl_boxes(boxes0, boxes1, boxes2, boxes3, lvl) + (size_t)b * n * 4;
    const unsigned long long* candp = cand + (size_t)blk * CAP;

    __shared__ unsigned long long arr[CAP];
    const int tid = threadIdx.x;
    unsigned cnt = counters[blk]; if (cnt > CAP) cnt = CAP;

    for (int i = tid; i < CAP; i += 1024)
        arr[i] = (i < (int)cnt) ? candp[i] : 0ull;
    __syncthreads();

    for (unsigned kk = 2; kk <= CAP; kk <<= 1) {
        for (unsigned j = kk >> 1; j > 0; j >>= 1) {
            for (unsigned i = tid; i < CAP; i += 1024) {
                unsigned p = i ^ j;
                if (p > i) {
                    unsigned long long a = arr[i], c = arr[p];
                    bool desc = ((i & kk) == 0);
                    if (desc ? (a < c) : (a > c)) { arr[i] = c; arr[p] = a; }
                }
            }
            __syncthreads();
        }
    }

    for (int r = tid; r < PRE_K; r += 1024) {
        unsigned long long c = arr[r];
        unsigned key = (unsigned)(c >> 32);
        int idx = (int)(~(unsigned)c);
        ws_scores[(size_t)blk * PRE_K + r] = key2f(key);
        float* dst = ws_boxes + ((size_t)blk * PRE_K + r) * 4;
        const float* src = bx + (size_t)idx * 4;
        dst[0] = src[0]; dst[1] = src[1]; dst[2] = src[2]; dst[3] = src[3];
    }
}

// ---------------------------------------------------------------------------
// Kernel 2a: parallel mask build, 8 blocks/level. Each wave owns 4 words
// (balanced sets {v,7-v,8+v,15-v}); lane's j-box register-cached -> only ONE
// broadcast float4 LDS read per row. Exact IEEE div runs only for words whose
// band-ballot (inter > 0.69*uni) is nonzero: inter<=fl(0.69*uni) proves
// fl(inter/uni) < 0.7f, so selection is bit-identical to always-divide.
// ---------------------------------------------------------------------------
__global__ __launch_bounds__(256) void mask_kernel(
    const float* __restrict__ ws_boxes,
    unsigned long long* __restrict__ ws_mask)   // [32][1000][16]
{
    const int blk  = blockIdx.x >> 3;    // (b,lvl)
    const int mb   = blockIdx.x & (MB - 1);
    const int tid  = threadIdx.x;
    const int lane = tid & 63;
    const int v    = tid >> 6;           // wave 0..3

    __shared__ float4 sbox[1024];

    const float4* bxp = (const float4*)(ws_boxes + (size_t)blk * NB * 4);
    for (int i = tid; i < 1024; i += 256)
        sbox[i] = (i < NB) ? bxp[i] : make_float4(0.f, 0.f, 0.f, 0.f);
    __syncthreads();

    unsigned long long* maskp = ws_mask + (size_t)blk * NB * NW;
    const int wset[4] = {v, 7 - v, 8 + v, 15 - v};
    #pragma unroll
    for (int s = 0; s < 4; ++s) {
        const int w = wset[s];
        const int j = w * 64 + lane;
        const float4 jb = sbox[j];
        const float aj = (jb.z - jb.x) * (jb.w - jb.y);
        const int rmax = min((w + 1) * 64, NB);
        for (int i = mb; i < rmax; i += MB) {
            float4 rb = sbox[i];                    // broadcast read
            float ai = (rb.z - rb.x) * (rb.w - rb.y);
            float iy1 = fmaxf(rb.x, jb.x);
            float ix1 = fmaxf(rb.y, jb.y);
            float iy2 = fminf(rb.z, jb.z);
            float ix2 = fminf(rb.w, jb.w);
            float ih = fmaxf(iy2 - iy1, 0.0f);
            float iw = fmaxf(ix2 - ix1, 0.0f);
            float inter = ih * iw;
            float uni = ai + aj - inter;
            bool amb = inter > 0.69f * uni;         // conservative band
            bool pred = false;
            if (__ballot(amb))                      // rare: exact IEEE div
                pred = (uni > 0.0f) && (inter / uni > 0.7f);
            pred = pred && (j > i);
            unsigned long long m = __ballot(pred);
            if (lane == 0) maskp[i * NW + w] = m;
        }
    }
}

// ---------------------------------------------------------------------------
// Kernel 2b: greedy NMS. Mask staged global->LDS with 1024 threads (8
// independent b128 loads/thread, latency pipelined). Serial pass on wave 0:
// readlane diagonal recurrence + branchless bit-masked applies (loads hoisted
// -- the R4 lesson: conditional-expression LDS loads compile branchy/serial).
// ---------------------------------------------------------------------------
__global__ __launch_bounds__(1024) void greedy_kernel(
    float* __restrict__ ws_scores,   // [32][1000] in-place
    float* __restrict__ ws_boxes,    // [32][1000][4] in-place
    const unsigned long long* __restrict__ ws_mask)
{
    const int blk  = blockIdx.x;
    const int tid  = threadIdx.x;
    const int lane = tid & 63;
    const int wv   = tid >> 6;       // 0..15

    __shared__ unsigned long long Mlds[1024 * NW];   // 131072 B (rows>=1000: garbage, never applied)
    __shared__ float4 sbox[NB];                      // 16000 B
    __shared__ float  ssc[NB];                       //  4000 B
    __shared__ unsigned long long keepw[NW];
    __shared__ int wprefix[NW];

    float* scp = ws_scores + (size_t)blk * NB;
    float* bxp = ws_boxes  + (size_t)blk * NB * 4;
    const unsigned long long* mrows = ws_mask + (size_t)blk * NB * NW;

    // ---- stage mask (16B vectors) + boxes + scores into LDS ----
    {
        const ulonglong2* src = (const ulonglong2*)mrows;
        ulonglong2* dst = (ulonglong2*)Mlds;
        for (int i = tid; i < NB * NW / 2; i += 1024) dst[i] = src[i];
    }
    for (int i = tid; i < NB; i += 1024) {
        sbox[i] = ((const float4*)bxp)[i];
        ssc[i]  = scp[i];
    }
    // initial keep bits: wave wv computes word wv
    {
        const int j = wv * 64 + lane;
        bool pred = (j < NB) && (scp[j] > 0.0f);
        unsigned long long bal = __ballot(pred);
        if (lane == 0) keepw[wv] = bal;
    }
    __syncthreads();

    // ---- chunked greedy pass on wave 0 ----
    if (tid < 64) {
        unsigned long long kp = (lane < NW) ? keepw[lane] : 0ull;
        for (int c = 0; c < NW; ++c) {
            unsigned long long w = __shfl(kp, c, 64);
            // lane i holds diag word of row c*64+i (one conflicted LDS read)
            unsigned long long dw = Mlds[(size_t)(c * 64 + lane) * NW + c];
            unsigned dlo = (unsigned)dw, dhi = (unsigned)(dw >> 32);
            #pragma unroll
            for (int i = 0; i < 64; ++i) {
                unsigned long long di =
                    ((unsigned long long)(unsigned)__builtin_amdgcn_readlane((int)dhi, i) << 32) |
                    (unsigned)__builtin_amdgcn_readlane((int)dlo, i);
                unsigned long long bit = (w >> i) & 1ull;
                w &= ~(di & (0ull - bit));           // branchless apply
            }
            if (lane == c) kp = w;
            // cross-chunk apply: lanes l>c accumulate kept rows' word l
            unsigned long long acc = 0ull;
            if (lane > c && lane < NW) {
                const unsigned long long* col = &Mlds[(size_t)(c * 64) * NW + lane];
                #pragma unroll 16
                for (int i = 0; i < 64; ++i) {
                    unsigned long long m = col[(size_t)i * NW];   // hoisted load
                    unsigned long long bit = (w >> i) & 1ull;
                    acc |= m & (0ull - bit);
                }
            }
            kp &= ~acc;
        }
        if (lane < NW) keepw[lane] = kp;
    }
    __syncthreads();
    if (tid == 0) {
        int acc = 0;
        for (int w = 0; w < NW; ++w) { wprefix[w] = acc; acc += __popcll(keepw[w]); }
    }
    __syncthreads();

    // ---- zero-fill then stable scatter of survivors (from LDS copies) ----
    for (int i = tid; i < NB; i += 1024) scp[i] = 0.0f;
    for (int i = tid; i < NB * 4; i += 1024) bxp[i] = 0.0f;
    __syncthreads();
    for (int i = tid; i < NB; i += 1024) {
        const int w = i >> 6;
        const unsigned long long kw = keepw[w];
        if ((kw >> (i & 63)) & 1ull) {
            int rank = wprefix[w] + __popcll(kw & ((1ull << (i & 63)) - 1ull));
            scp[rank] = ssc[i];
            float4 bb = sbox[i];
            float* dst = bxp + (size_t)rank * 4;
            dst[0] = bb.x; dst[1] = bb.y; dst[2] = bb.z; dst[3] = bb.w;
        }
    }
}

// ---------------------------------------------------------------------------
// Kernel 3: final top-1000 by 4-way merge-rank. Each level's 1000-entry list
// is already sorted DESC by the exact final composite (score key, then
// concatenated index asc), so rank(e) = r + sum over other lists of
// count(> c) via binary search. Ranks unique -> scatter == full sort.
// One block per (b,lvl); batch's 4 lists staged in LDS (32 KB).
// ---------------------------------------------------------------------------
__global__ __launch_bounds__(1024) void final_merge_kernel(
    const float* __restrict__ ws_scores,  // [8][4][1000]
    const float* __restrict__ ws_boxes,   // [8][4000][4]
    float* __restrict__ out)              // rois (8*1000*4) then scores (8*1000)
{
    const int blk = blockIdx.x;          // b*4 + lvl
    const int b   = blk >> 2;
    const int lvl = blk & 3;
    const int tid = threadIdx.x;

    __shared__ unsigned long long lists[NLVL][PRE_K];   // 32000 B

    // stage all 4 lists of batch b as final composites
    for (int i = tid; i < TOT; i += 1024) {
        unsigned u = f2key(ws_scores[(size_t)b * TOT + i]);
        lists[i / PRE_K][i % PRE_K] =
            ((unsigned long long)u << 32) | (unsigned)(~i);
    }
    __syncthreads();

    float* out_rois   = out;            // (8,1000,4)
    float* out_scores = out + 32000;    // (8,1000)

    for (int r = tid; r < PRE_K; r += 1024) {
        const unsigned long long c = lists[lvl][r];
        int rank = r;
        #pragma unroll
        for (int l = 0; l < NLVL; ++l) {
            if (l == lvl) continue;
            // count of elements in descending lists[l] with composite > c
            int lo = 0, hi = PRE_K;
            while (lo < hi) {
                int mid = (lo + hi) >> 1;
                if (lists[l][mid] > c) lo = mid + 1; else hi = mid;
            }
            rank += lo;
        }
        if (rank < PRE_K) {
            out_scores[(size_t)b * PRE_K + rank] = key2f((unsigned)(c >> 32));
            const int pos = lvl * PRE_K + r;     // == ~(unsigned)c
            const float4 bb = ((const float4*)ws_boxes)[(size_t)b * TOT + pos];
            float* dst = out_rois + ((size_t)b * PRE_K + rank) * 4;
            dst[0] = bb.x; dst[1] = bb.y; dst[2] = bb.z; dst[3] = bb.w;
        }
    }
}

// ---------------------------------------------------------------------------
extern "C" void kernel_launch(void* const* d_in, const int* in_sizes, int n_in,
                              void* d_out, int out_size, void* d_ws, size_t ws_size,
                              hipStream_t stream) {
    // setup_inputs() dict order: boxes_p2, scores_p2, boxes_p3, scores_p3,
    //                            boxes_p4, scores_p4, boxes_p5, scores_p5
    const float* boxes0  = (const float*)d_in[0];
    const float* scores0 = (const float*)d_in[1];
    const float* boxes1  = (const float*)d_in[2];
    const float* scores1 = (const float*)d_in[3];
    const float* boxes2  = (const float*)d_in[4];
    const float* scores2 = (const float*)d_in[5];
    const float* boxes3  = (const float*)d_in[6];
    const float* scores3 = (const float*)d_in[7];
    float* out = (float*)d_out;

    // ws carve: scores [32*1000] | boxes [32*1000*4] | mask [32*1000*16 u64]
    // topk scratch (cand/ghist/counters/thresh) OVERLAYS the mask region:
    // all of it is dead before mask_kernel writes.
    char* base = (char*)d_ws;
    float* ws_scores = (float*)base;                                     // 128000 B
    float* ws_boxes  = (float*)(base + 128000);                          // 512000 B
    unsigned long long* ws_mask = (unsigned long long*)(base + 640000);  // 4096000 B
    // overlay inside mask region:
    unsigned long long* cand = (unsigned long long*)(base + 640000);     // 524288 B
    unsigned* ghist    = (unsigned*)(base + 1164288);                    // 1048576 B
    unsigned* counters = (unsigned*)(base + 2212864);                    // 128 B
    unsigned* thresh   = (unsigned*)(base + 2212992);                    // 128 B

    init_kernel<<<128, 512, 0, stream>>>(ghist);
    hist_kernel<<<BATCH * NLVL * HB, 512, 0, stream>>>(
        scores0, scores1, scores2, scores3, ghist);
    select_kernel<<<BATCH * NLVL, 256, 0, stream>>>(ghist, thresh, counters);
    collect_kernel<<<BATCH * NLVL * HB, 512, 0, stream>>>(
        scores0, scores1, scores2, scores3, thresh, counters, cand);
    sortemit_kernel<<<BATCH * NLVL, 1024, 0, stream>>>(
        boxes0, boxes1, boxes2, boxes3, counters, cand, ws_scores, ws_boxes);
    mask_kernel<<<BATCH * NLVL * MB, 256, 0, stream>>>(ws_boxes, ws_mask);
    greedy_kernel<<<BATCH * NLVL, 1024, 0, stream>>>(ws_scores, ws_boxes, ws_mask);
    final_merge_kernel<<<BATCH * NLVL, 1024, 0, stream>>>(ws_scores, ws_boxes, out);
}

// Round 8
// 176.386 us; speedup vs baseline: 2.5596x; 1.0732x over previous
//
#include <hip/hip_runtime.h>

#define PRE_K 1000
#define CAP   2048      // candidate buffer per level (>= PRE_K + max bin, pow2)
#define NBIN  8192      // 13-bit key-prefix histogram bins
#define NB    1000      // boxes per level after pre-NMS topk
#define NW    16        // 64-bit words covering NB bits (16*64 = 1024)
#define TOT   4000      // concatenated entries per batch
#define NLVL  4
#define BATCH 8
#define HB    8         // blocks per (b,lvl) for hist/collect
#define MBM   16        // blocks per (b,lvl) for mask build

__device__ __forceinline__ unsigned f2key(float f) {
    unsigned u = __float_as_uint(f);
    return (u & 0x80000000u) ? ~u : (u | 0x80000000u);   // monotonic ascending
}
__device__ __forceinline__ float key2f(unsigned k) {
    unsigned u = (k & 0x80000000u) ? (k & 0x7FFFFFFFu) : ~k;
    return __uint_as_float(u);
}
__device__ __forceinline__ const float* lvl_scores(
    const float* s0, const float* s1, const float* s2, const float* s3, int lvl) {
    switch (lvl) { case 0: return s0; case 1: return s1; case 2: return s2; default: return s3; }
}
__device__ __forceinline__ const float* lvl_boxes(
    const float* b0, const float* b1, const float* b2, const float* b3, int lvl) {
    switch (lvl) { case 0: return b0; case 1: return b1; case 2: return b2; default: return b3; }
}
__device__ __forceinline__ int lvl_n(int lvl) {
    const int sizes[4] = {196608, 49152, 12288, 3072};
    return sizes[lvl];
}
__device__ __forceinline__ float bcast_f(float v, int i) {
    return __int_as_float(__builtin_amdgcn_readlane(__float_as_int(v), i));
}

// ---------------------------------------------------------------------------
// T0: zero global histograms
// ---------------------------------------------------------------------------
__global__ __launch_bounds__(512) void init_kernel(unsigned* __restrict__ ghist) {
    const int stride = gridDim.x * 512;
    for (int i = blockIdx.x * 512 + threadIdx.x; i < 32 * NBIN; i += stride)
        ghist[i] = 0u;
}

// ---------------------------------------------------------------------------
// T1: per-(b,lvl) 13-bit-prefix histogram. float4 loads; 2 bank-replicas to
// halve hot-bin LDS atomic serialization (N(0,1) scores concentrate bins).
// ---------------------------------------------------------------------------
__global__ __launch_bounds__(512) void hist_kernel(
    const float* __restrict__ scores0, const float* __restrict__ scores1,
    const float* __restrict__ scores2, const float* __restrict__ scores3,
    unsigned* __restrict__ ghist)      // [32][NBIN]
{
    const int blk = blockIdx.x / HB;   // b*4 + lvl
    const int hb  = blockIdx.x % HB;
    const int b   = blk >> 2;
    const int lvl = blk & 3;
    const int n   = lvl_n(lvl);
    const float* sc = lvl_scores(scores0, scores1, scores2, scores3, lvl) + (size_t)b * n;

    __shared__ unsigned lhist[2][NBIN];   // 64 KB
    const int tid = threadIdx.x;
    const int rep = (tid >> 6) & 1;       // wave-uniform replica
    for (int i = tid; i < 2 * NBIN; i += 512) (&lhist[0][0])[i] = 0u;
    __syncthreads();

    const float4* sc4 = (const float4*)sc;
    const int n4 = n >> 2;                // all level sizes divisible by 4
    for (int i = hb * 512 + tid; i < n4; i += HB * 512) {
        float4 v = sc4[i];
        atomicAdd(&lhist[rep][f2key(v.x) >> 19], 1u);
        atomicAdd(&lhist[rep][f2key(v.y) >> 19], 1u);
        atomicAdd(&lhist[rep][f2key(v.z) >> 19], 1u);
        atomicAdd(&lhist[rep][f2key(v.w) >> 19], 1u);
    }
    __syncthreads();

    unsigned* gh = ghist + (size_t)blk * NBIN;
    for (int i = tid; i < NBIN; i += 512) {
        unsigned v = lhist[0][i] + lhist[1][i];
        if (v) atomicAdd(&gh[i], v);
    }
}

// ---------------------------------------------------------------------------
// T2: per-(b,lvl) threshold-bin selection (top-PRE_K boundary); zero counters
// ---------------------------------------------------------------------------
__global__ __launch_bounds__(256) void select_kernel(
    const unsigned* __restrict__ ghist,   // [32][NBIN]
    unsigned* __restrict__ thresh,        // [32]
    unsigned* __restrict__ counters)      // [32]
{
    const int blk = blockIdx.x;
    const int tid = threadIdx.x;
    const unsigned* gh = ghist + (size_t)blk * NBIN;

    __shared__ unsigned csum[256];
    __shared__ int s_chunk;
    __shared__ unsigned s_before;

    // chunk sums: thread t covers bins [t*32, t*32+32)
    unsigned s = 0;
    #pragma unroll 8
    for (int k = 0; k < 32; ++k) s += gh[tid * 32 + k];
    csum[tid] = s;
    __syncthreads();

    // suffix over chunks ABOVE tid (LDS broadcast reads)
    unsigned suf = 0;
    for (int c = tid + 1; c < 256; ++c) suf += csum[c];
    // unique chunk where the top-PRE_K boundary falls
    if (suf < PRE_K && suf + csum[tid] >= PRE_K) { s_chunk = tid; s_before = suf; }
    __syncthreads();

    if (tid == 0) {
        int C = s_chunk;
        unsigned acc = s_before;
        int T = C * 32;
        for (int bin = C * 32 + 31; bin >= C * 32; --bin) {
            acc += gh[bin];
            if (acc >= PRE_K) { T = bin; break; }
        }
        thresh[blk]   = (unsigned)T;
        counters[blk] = 0u;       // zero collect counter for this level
    }
}

// ---------------------------------------------------------------------------
// T3: collect candidates with key-bin >= threshold. LDS-buffered per block,
// ONE global atomic per block (order across blocks irrelevant: sorted later,
// stable tie-break lives in the composite key's ~idx).
// ---------------------------------------------------------------------------
__global__ __launch_bounds__(512) void collect_kernel(
    const float* __restrict__ scores0, const float* __restrict__ scores1,
    const float* __restrict__ scores2, const float* __restrict__ scores3,
    const unsigned* __restrict__ thresh,
    unsigned* __restrict__ counters,
    unsigned long long* __restrict__ cand)   // [32][CAP]
{
    const int blk = blockIdx.x / HB;
    const int hb  = blockIdx.x % HB;
    const int b   = blk >> 2;
    const int lvl = blk & 3;
    const int n   = lvl_n(lvl);
    const float* sc = lvl_scores(scores0, scores1, scores2, scores3, lvl) + (size_t)b * n;
    const unsigned T = thresh[blk];
    unsigned long long* candp = cand + (size_t)blk * CAP;

    __shared__ unsigned long long cbuf[CAP];
    __shared__ unsigned ccnt, cbase;

    const int tid  = threadIdx.x;
    const int lane = tid & 63;
    if (tid == 0) ccnt = 0;
    __syncthreads();

    for (int i = hb * 512 + tid; i < n; i += HB * 512) {
        unsigned key = f2key(sc[i]);
        bool pred = (key >> 19) >= T;
        unsigned long long act = __ballot(pred);
        if (act) {
            int leader = __ffsll((long long)act) - 1;
            unsigned base = 0;
            if (lane == leader) base = atomicAdd(&ccnt, (unsigned)__popcll(act));
            base = __shfl(base, leader, 64);
            if (pred) {
                unsigned pos = base + (unsigned)__popcll(act & ((1ull << lane) - 1ull));
                if (pos < CAP)
                    cbuf[pos] = ((unsigned long long)key << 32) | (unsigned)(~i);
            }
        }
    }
    __syncthreads();
    unsigned cnt = ccnt; if (cnt > CAP) cnt = CAP;
    if (tid == 0) cbase = atomicAdd(&counters[blk], cnt);
    __syncthreads();
    const unsigned gb = cbase;
    for (unsigned i = tid; i < cnt; i += 512) {
        unsigned p = gb + i;
        if (p < CAP) candp[p] = cbuf[i];
    }
}

// ---------------------------------------------------------------------------
// T4: per-(b,lvl) bitonic sort of candidates, emit top-1000 scores + boxes
// ---------------------------------------------------------------------------
__global__ __launch_bounds__(1024) void sortemit_kernel(
    const float* __restrict__ boxes0, const float* __restrict__ boxes1,
    const float* __restrict__ boxes2, const float* __restrict__ boxes3,
    const unsigned* __restrict__ counters,
    const unsigned long long* __restrict__ cand,
    float* __restrict__ ws_scores,   // [32][1000]
    float* __restrict__ ws_boxes)    // [32][1000][4]
{
    const int blk = blockIdx.x;
    const int b   = blk >> 2;
    const int lvl = blk & 3;
    const int n   = lvl_n(lvl);
    const float* bx = lvl_boxes(boxes0, boxes1, boxes2, boxes3, lvl) + (size_t)b * n * 4;
    const unsigned long long* candp = cand + (size_t)blk * CAP;

    __shared__ unsigned long long arr[CAP];
    const int tid = threadIdx.x;
    unsigned cnt = counters[blk]; if (cnt > CAP) cnt = CAP;

    for (int i = tid; i < CAP; i += 1024)
        arr[i] = (i < (int)cnt) ? candp[i] : 0ull;
    __syncthreads();

    for (unsigned kk = 2; kk <= CAP; kk <<= 1) {
        for (unsigned j = kk >> 1; j > 0; j >>= 1) {
            for (unsigned i = tid; i < CAP; i += 1024) {
                unsigned p = i ^ j;
                if (p > i) {
                    unsigned long long a = arr[i], c = arr[p];
                    bool desc = ((i & kk) == 0);
                    if (desc ? (a < c) : (a > c)) { arr[i] = c; arr[p] = a; }
                }
            }
            __syncthreads();
        }
    }

    for (int r = tid; r < PRE_K; r += 1024) {
        unsigned long long c = arr[r];
        unsigned key = (unsigned)(c >> 32);
        int idx = (int)(~(unsigned)c);
        ws_scores[(size_t)blk * PRE_K + r] = key2f(key);
        float* dst = ws_boxes + ((size_t)blk * PRE_K + r) * 4;
        const float* src = bx + (size_t)idx * 4;
        dst[0] = src[0]; dst[1] = src[1]; dst[2] = src[2]; dst[3] = src[3];
    }
}

// ---------------------------------------------------------------------------
// Kernel 2a: mask build as 136 (word, row-block) 64x64 tile-tasks per level.
// Inner loop has NO LDS access: lane's j-box in regs; row boxes preloaded to
// lane regs (one conflict-free b128 read) and broadcast via v_readlane
// (uniform index, VALU-cheap -- kills the 120cy ds_read dependent chain of
// R7). Branchless EXACT threshold test in double: fl(inter/uni) > 0.7f
//  <=>  2*inter >= (c1+c2)*uni  (c1=0.7f, c2=nextafter; RNE tie rounds to
// even c2 > 0.7f -> ties suppress; 25b x 24b products exact in f64).
// Word accumulated via lane==i select; ONE batched store per task.
// ---------------------------------------------------------------------------
__global__ __launch_bounds__(256) void mask_kernel(
    const float* __restrict__ ws_boxes,
    unsigned long long* __restrict__ ws_mask)   // [32][1000][16]
{
    const int blk  = blockIdx.x / MBM;    // (b,lvl)
    const int mb   = blockIdx.x % MBM;
    const int tid  = threadIdx.x;
    const int lane = tid & 63;
    const int wv   = tid >> 6;            // wave 0..3

    __shared__ float4 sbox[1024];

    const float4* bxp = (const float4*)(ws_boxes + (size_t)blk * NB * 4);
    for (int i = tid; i < 1024; i += 256)
        sbox[i] = (i < NB) ? bxp[i] : make_float4(0.f, 0.f, 0.f, 0.f);
    __syncthreads();

    unsigned long long* maskp = ws_mask + (size_t)blk * NB * NW;
    const double CSUM = (double)__uint_as_float(0x3F333333u)
                      + (double)__uint_as_float(0x3F333334u);   // exact 2*midpoint

    for (int t = mb * 4 + wv; t < 136; t += MBM * 4) {
        // decode t -> (w, rb): word w has row-blocks 0..w
        int w = 0, acc = 0;
        while (acc + w + 1 <= t) { acc += w + 1; ++w; }
        const int rb = t - acc;

        const int j = w * 64 + lane;
        const float4 jb = sbox[j];                    // zeros for j>=NB -> pred false
        const float aj = (jb.z - jb.x) * (jb.w - jb.y);

        const int rbase = rb * 64;
        const float4 rbx = sbox[rbase + lane];        // lane l owns row rbase+l
        const float ra = (rbx.z - rbx.x) * (rbx.w - rbx.y);
        const int ilim = min(64, NB - rbase);

        unsigned long long myw = 0ull;
        for (int i = 0; i < ilim; ++i) {
            const float y1 = bcast_f(rbx.x, i);
            const float x1 = bcast_f(rbx.y, i);
            const float y2 = bcast_f(rbx.z, i);
            const float x2 = bcast_f(rbx.w, i);
            const float ai = bcast_f(ra, i);
            float iy1 = fmaxf(y1, jb.x);
            float ix1 = fmaxf(x1, jb.y);
            float iy2 = fminf(y2, jb.z);
            float ix2 = fminf(x2, jb.w);
            float ih = fmaxf(iy2 - iy1, 0.0f);
            float iw = fmaxf(ix2 - ix1, 0.0f);
            float inter = ih * iw;
            float uni = ai + aj - inter;
            bool pred = (uni > 0.0f) &&
                        (2.0 * (double)inter >= CSUM * (double)uni) &&
                        (j > rbase + i);
            unsigned long long m = __ballot(pred);
            if (lane == i) myw = m;                   // cndmask, no branch
        }
        if (lane < ilim)
            maskp[(size_t)(rbase + lane) * NW + w] = myw;
    }
}

// ---------------------------------------------------------------------------
// Kernel 2b: greedy NMS. Mask staged global->LDS with 1024 threads (8
// independent b128 loads/thread, latency pipelined). Serial pass on wave 0:
// readlane diagonal recurrence + branchless bit-masked applies (loads hoisted
// -- the R4 lesson: conditional-expression LDS loads compile branchy/serial).
// ---------------------------------------------------------------------------
__global__ __launch_bounds__(1024) void greedy_kernel(
    float* __restrict__ ws_scores,   // [32][1000] in-place
    float* __restrict__ ws_boxes,    // [32][1000][4] in-place
    const unsigned long long* __restrict__ ws_mask)
{
    const int blk  = blockIdx.x;
    const int tid  = threadIdx.x;
    const int lane = tid & 63;
    const int wv   = tid >> 6;       // 0..15

    __shared__ unsigned long long Mlds[1024 * NW];   // 131072 B (rows>=1000: garbage, never applied)
    __shared__ float4 sbox[NB];                      // 16000 B
    __shared__ float  ssc[NB];                       //  4000 B
    __shared__ unsigned long long keepw[NW];
    __shared__ int wprefix[NW];

    float* scp = ws_scores + (size_t)blk * NB;
    float* bxp = ws_boxes  + (size_t)blk * NB * 4;
    const unsigned long long* mrows = ws_mask + (size_t)blk * NB * NW;

    // ---- stage mask (16B vectors) + boxes + scores into LDS ----
    {
        const ulonglong2* src = (const ulonglong2*)mrows;
        ulonglong2* dst = (ulonglong2*)Mlds;
        for (int i = tid; i < NB * NW / 2; i += 1024) dst[i] = src[i];
    }
    for (int i = tid; i < NB; i += 1024) {
        sbox[i] = ((const float4*)bxp)[i];
        ssc[i]  = scp[i];
    }
    // initial keep bits: wave wv computes word wv
    {
        const int j = wv * 64 + lane;
        bool pred = (j < NB) && (scp[j] > 0.0f);
        unsigned long long bal = __ballot(pred);
        if (lane == 0) keepw[wv] = bal;
    }
    __syncthreads();

    // ---- chunked greedy pass on wave 0 ----
    if (tid < 64) {
        unsigned long long kp = (lane < NW) ? keepw[lane] : 0ull;
        for (int c = 0; c < NW; ++c) {
            unsigned long long w = __shfl(kp, c, 64);
            // lane i holds diag word of row c*64+i (one conflicted LDS read)
            unsigned long long dw = Mlds[(size_t)(c * 64 + lane) * NW + c];
            unsigned dlo = (unsigned)dw, dhi = (unsigned)(dw >> 32);
            #pragma unroll
            for (int i = 0; i < 64; ++i) {
                unsigned long long di =
                    ((unsigned long long)(unsigned)__builtin_amdgcn_readlane((int)dhi, i) << 32) |
                    (unsigned)__builtin_amdgcn_readlane((int)dlo, i);
                unsigned long long bit = (w >> i) & 1ull;
                w &= ~(di & (0ull - bit));           // branchless apply
            }
            if (lane == c) kp = w;
            // cross-chunk apply: lanes l>c accumulate kept rows' word l
            unsigned long long acc = 0ull;
            if (lane > c && lane < NW) {
                const unsigned long long* col = &Mlds[(size_t)(c * 64) * NW + lane];
                #pragma unroll 16
                for (int i = 0; i < 64; ++i) {
                    unsigned long long m = col[(size_t)i * NW];   // hoisted load
                    unsigned long long bit = (w >> i) & 1ull;
                    acc |= m & (0ull - bit);
                }
            }
            kp &= ~acc;
        }
        if (lane < NW) keepw[lane] = kp;
    }
    __syncthreads();
    if (tid == 0) {
        int acc = 0;
        for (int w = 0; w < NW; ++w) { wprefix[w] = acc; acc += __popcll(keepw[w]); }
    }
    __syncthreads();

    // ---- zero-fill then stable scatter of survivors (from LDS copies) ----
    for (int i = tid; i < NB; i += 1024) scp[i] = 0.0f;
    for (int i = tid; i < NB * 4; i += 1024) bxp[i] = 0.0f;
    __syncthreads();
    for (int i = tid; i < NB; i += 1024) {
        const int w = i >> 6;
        const unsigned long long kw = keepw[w];
        if ((kw >> (i & 63)) & 1ull) {
            int rank = wprefix[w] + __popcll(kw & ((1ull << (i & 63)) - 1ull));
            scp[rank] = ssc[i];
            float4 bb = sbox[i];
            float* dst = bxp + (size_t)rank * 4;
            dst[0] = bb.x; dst[1] = bb.y; dst[2] = bb.z; dst[3] = bb.w;
        }
    }
}

// ---------------------------------------------------------------------------
// Kernel 3: final top-1000 by 4-way merge-rank. Each level's 1000-entry list
// is already sorted DESC by the exact final composite (score key, then
// concatenated index asc), so rank(e) = r + sum over other lists of
// count(> c) via binary search. Ranks unique -> scatter == full sort.
// One block per (b,lvl); batch's 4 lists staged in LDS (32 KB).
// ---------------------------------------------------------------------------
__global__ __launch_bounds__(1024) void final_merge_kernel(
    const float* __restrict__ ws_scores,  // [8][4][1000]
    const float* __restrict__ ws_boxes,   // [8][4000][4]
    float* __restrict__ out)              // rois (8*1000*4) then scores (8*1000)
{
    const int blk = blockIdx.x;          // b*4 + lvl
    const int b   = blk >> 2;
    const int lvl = blk & 3;
    const int tid = threadIdx.x;

    __shared__ unsigned long long lists[NLVL][PRE_K];   // 32000 B

    // stage all 4 lists of batch b as final composites
    for (int i = tid; i < TOT; i += 1024) {
        unsigned u = f2key(ws_scores[(size_t)b * TOT + i]);
        lists[i / PRE_K][i % PRE_K] =
            ((unsigned long long)u << 32) | (unsigned)(~i);
    }
    __syncthreads();

    float* out_rois   = out;            // (8,1000,4)
    float* out_scores = out + 32000;    // (8,1000)

    for (int r = tid; r < PRE_K; r += 1024) {
        const unsigned long long c = lists[lvl][r];
        int rank = r;
        #pragma unroll
        for (int l = 0; l < NLVL; ++l) {
            if (l == lvl) continue;
            // count of elements in descending lists[l] with composite > c
            int lo = 0, hi = PRE_K;
            while (lo < hi) {
                int mid = (lo + hi) >> 1;
                if (lists[l][mid] > c) lo = mid + 1; else hi = mid;
            }
            rank += lo;
        }
        if (rank < PRE_K) {
            out_scores[(size_t)b * PRE_K + rank] = key2f((unsigned)(c >> 32));
            const int pos = lvl * PRE_K + r;     // == ~(unsigned)c
            const float4 bb = ((const float4*)ws_boxes)[(size_t)b * TOT + pos];
            float* dst = out_rois + ((size_t)b * PRE_K + rank) * 4;
            dst[0] = bb.x; dst[1] = bb.y; dst[2] = bb.z; dst[3] = bb.w;
        }
    }
}

// ---------------------------------------------------------------------------
extern "C" void kernel_launch(void* const* d_in, const int* in_sizes, int n_in,
                              void* d_out, int out_size, void* d_ws, size_t ws_size,
                              hipStream_t stream) {
    // setup_inputs() dict order: boxes_p2, scores_p2, boxes_p3, scores_p3,
    //                            boxes_p4, scores_p4, boxes_p5, scores_p5
    const float* boxes0  = (const float*)d_in[0];
    const float* scores0 = (const float*)d_in[1];
    const float* boxes1  = (const float*)d_in[2];
    const float* scores1 = (const float*)d_in[3];
    const float* boxes2  = (const float*)d_in[4];
    const float* scores2 = (const float*)d_in[5];
    const float* boxes3  = (const float*)d_in[6];
    const float* scores3 = (const float*)d_in[7];
    float* out = (float*)d_out;

    // ws carve: scores [32*1000] | boxes [32*1000*4] | mask [32*1000*16 u64]
    // topk scratch (cand/ghist/counters/thresh) OVERLAYS the mask region:
    // all of it is dead before mask_kernel writes.
    char* base = (char*)d_ws;
    float* ws_scores = (float*)base;                                     // 128000 B
    float* ws_boxes  = (float*)(base + 128000);                          // 512000 B
    unsigned long long* ws_mask = (unsigned long long*)(base + 640000);  // 4096000 B
    // overlay inside mask region:
    unsigned long long* cand = (unsigned long long*)(base + 640000);     // 524288 B
    unsigned* ghist    = (unsigned*)(base + 1164288);                    // 1048576 B
    unsigned* counters = (unsigned*)(base + 2212864);                    // 128 B
    unsigned* thresh   = (unsigned*)(base + 2212992);                    // 128 B

    init_kernel<<<128, 512, 0, stream>>>(ghist);
    hist_kernel<<<BATCH * NLVL * HB, 512, 0, stream>>>(
        scores0, scores1, scores2, scores3, ghist);
    select_kernel<<<BATCH * NLVL, 256, 0, stream>>>(ghist, thresh, counters);
    collect_kernel<<<BATCH * NLVL * HB, 512, 0, stream>>>(
        scores0, scores1, scores2, scores3, thresh, counters, cand);
    sortemit_kernel<<<BATCH * NLVL, 1024, 0, stream>>>(
        boxes0, boxes1, boxes2, boxes3, counters, cand, ws_scores, ws_boxes);
    mask_kernel<<<BATCH * NLVL * MBM, 256, 0, stream>>>(ws_boxes, ws_mask);
    greedy_kernel<<<BATCH * NLVL, 1024, 0, stream>>>(ws_scores, ws_boxes, ws_mask);
    final_merge_kernel<<<BATCH * NLVL, 1024, 0, stream>>>(ws_scores, ws_boxes, out);
}

// Round 9
// 127.173 us; speedup vs baseline: 3.5501x; 1.3870x over previous
//
#include <hip/hip_runtime.h>

#define PRE_K 1000
#define CAP   2048      // candidate buffer per level (>= PRE_K + max bin, pow2)
#define NBIN  8192      // 13-bit key-prefix histogram bins
#define NB    1000      // boxes per level after pre-NMS topk
#define NW    16        // 64-bit words covering NB bits (16*64 = 1024)
#define TOT   4000      // concatenated entries per batch
#define NLVL  4
#define BATCH 8
#define HB    8         // blocks per (b,lvl) for hist/collect
#define MBM   16        // blocks per (b,lvl) for mask build

__device__ __forceinline__ unsigned f2key(float f) {
    unsigned u = __float_as_uint(f);
    return (u & 0x80000000u) ? ~u : (u | 0x80000000u);   // monotonic ascending
}
__device__ __forceinline__ float key2f(unsigned k) {
    unsigned u = (k & 0x80000000u) ? (k & 0x7FFFFFFFu) : ~k;
    return __uint_as_float(u);
}
__device__ __forceinline__ const float* lvl_scores(
    const float* s0, const float* s1, const float* s2, const float* s3, int lvl) {
    switch (lvl) { case 0: return s0; case 1: return s1; case 2: return s2; default: return s3; }
}
__device__ __forceinline__ const float* lvl_boxes(
    const float* b0, const float* b1, const float* b2, const float* b3, int lvl) {
    switch (lvl) { case 0: return b0; case 1: return b1; case 2: return b2; default: return b3; }
}
__device__ __forceinline__ int lvl_n(int lvl) {
    const int sizes[4] = {196608, 49152, 12288, 3072};
    return sizes[lvl];
}
__device__ __forceinline__ float bcast_f(float v, int i) {
    return __int_as_float(__builtin_amdgcn_readlane(__float_as_int(v), i));
}

// ---------------------------------------------------------------------------
// T0: zero global histograms + nonzero-row bitmaps
// ---------------------------------------------------------------------------
__global__ __launch_bounds__(512) void init_kernel(
    unsigned* __restrict__ ghist, unsigned long long* __restrict__ ws_nz) {
    const int stride = gridDim.x * 512;
    for (int i = blockIdx.x * 512 + threadIdx.x; i < 32 * NBIN; i += stride)
        ghist[i] = 0u;
    for (int i = blockIdx.x * 512 + threadIdx.x; i < 32 * NW; i += stride)
        ws_nz[i] = 0ull;
}

// ---------------------------------------------------------------------------
// T1: per-(b,lvl) 13-bit-prefix histogram. float4 loads; 2 bank-replicas to
// halve hot-bin LDS atomic serialization (N(0,1) scores concentrate bins).
// ---------------------------------------------------------------------------
__global__ __launch_bounds__(512) void hist_kernel(
    const float* __restrict__ scores0, const float* __restrict__ scores1,
    const float* __restrict__ scores2, const float* __restrict__ scores3,
    unsigned* __restrict__ ghist)      // [32][NBIN]
{
    const int blk = blockIdx.x / HB;   // b*4 + lvl
    const int hb  = blockIdx.x % HB;
    const int b   = blk >> 2;
    const int lvl = blk & 3;
    const int n   = lvl_n(lvl);
    const float* sc = lvl_scores(scores0, scores1, scores2, scores3, lvl) + (size_t)b * n;

    __shared__ unsigned lhist[2][NBIN];   // 64 KB
    const int tid = threadIdx.x;
    const int rep = (tid >> 6) & 1;       // wave-uniform replica
    for (int i = tid; i < 2 * NBIN; i += 512) (&lhist[0][0])[i] = 0u;
    __syncthreads();

    const float4* sc4 = (const float4*)sc;
    const int n4 = n >> 2;                // all level sizes divisible by 4
    for (int i = hb * 512 + tid; i < n4; i += HB * 512) {
        float4 v = sc4[i];
        atomicAdd(&lhist[rep][f2key(v.x) >> 19], 1u);
        atomicAdd(&lhist[rep][f2key(v.y) >> 19], 1u);
        atomicAdd(&lhist[rep][f2key(v.z) >> 19], 1u);
        atomicAdd(&lhist[rep][f2key(v.w) >> 19], 1u);
    }
    __syncthreads();

    unsigned* gh = ghist + (size_t)blk * NBIN;
    for (int i = tid; i < NBIN; i += 512) {
        unsigned v = lhist[0][i] + lhist[1][i];
        if (v) atomicAdd(&gh[i], v);
    }
}

// ---------------------------------------------------------------------------
// T2: per-(b,lvl) threshold-bin selection (top-PRE_K boundary); zero counters
// ---------------------------------------------------------------------------
__global__ __launch_bounds__(256) void select_kernel(
    const unsigned* __restrict__ ghist,   // [32][NBIN]
    unsigned* __restrict__ thresh,        // [32]
    unsigned* __restrict__ counters)      // [32]
{
    const int blk = blockIdx.x;
    const int tid = threadIdx.x;
    const unsigned* gh = ghist + (size_t)blk * NBIN;

    __shared__ unsigned csum[256];
    __shared__ int s_chunk;
    __shared__ unsigned s_before;

    // chunk sums: thread t covers bins [t*32, t*32+32)
    unsigned s = 0;
    #pragma unroll 8
    for (int k = 0; k < 32; ++k) s += gh[tid * 32 + k];
    csum[tid] = s;
    __syncthreads();

    // suffix over chunks ABOVE tid (LDS broadcast reads)
    unsigned suf = 0;
    for (int c = tid + 1; c < 256; ++c) suf += csum[c];
    // unique chunk where the top-PRE_K boundary falls
    if (suf < PRE_K && suf + csum[tid] >= PRE_K) { s_chunk = tid; s_before = suf; }
    __syncthreads();

    if (tid == 0) {
        int C = s_chunk;
        unsigned acc = s_before;
        int T = C * 32;
        for (int bin = C * 32 + 31; bin >= C * 32; --bin) {
            acc += gh[bin];
            if (acc >= PRE_K) { T = bin; break; }
        }
        thresh[blk]   = (unsigned)T;
        counters[blk] = 0u;       // zero collect counter for this level
    }
}

// ---------------------------------------------------------------------------
// T3: collect candidates with key-bin >= threshold. LDS-buffered per block,
// ONE global atomic per block (order across blocks irrelevant: sorted later,
// stable tie-break lives in the composite key's ~idx).
// ---------------------------------------------------------------------------
__global__ __launch_bounds__(512) void collect_kernel(
    const float* __restrict__ scores0, const float* __restrict__ scores1,
    const float* __restrict__ scores2, const float* __restrict__ scores3,
    const unsigned* __restrict__ thresh,
    unsigned* __restrict__ counters,
    unsigned long long* __restrict__ cand)   // [32][CAP]
{
    const int blk = blockIdx.x / HB;
    const int hb  = blockIdx.x % HB;
    const int b   = blk >> 2;
    const int lvl = blk & 3;
    const int n   = lvl_n(lvl);
    const float* sc = lvl_scores(scores0, scores1, scores2, scores3, lvl) + (size_t)b * n;
    const unsigned T = thresh[blk];
    unsigned long long* candp = cand + (size_t)blk * CAP;

    __shared__ unsigned long long cbuf[CAP];
    __shared__ unsigned ccnt, cbase;

    const int tid  = threadIdx.x;
    const int lane = tid & 63;
    if (tid == 0) ccnt = 0;
    __syncthreads();

    for (int i = hb * 512 + tid; i < n; i += HB * 512) {
        unsigned key = f2key(sc[i]);
        bool pred = (key >> 19) >= T;
        unsigned long long act = __ballot(pred);
        if (act) {
            int leader = __ffsll((long long)act) - 1;
            unsigned base = 0;
            if (lane == leader) base = atomicAdd(&ccnt, (unsigned)__popcll(act));
            base = __shfl(base, leader, 64);
            if (pred) {
                unsigned pos = base + (unsigned)__popcll(act & ((1ull << lane) - 1ull));
                if (pos < CAP)
                    cbuf[pos] = ((unsigned long long)key << 32) | (unsigned)(~i);
            }
        }
    }
    __syncthreads();
    unsigned cnt = ccnt; if (cnt > CAP) cnt = CAP;
    if (tid == 0) cbase = atomicAdd(&counters[blk], cnt);
    __syncthreads();
    const unsigned gb = cbase;
    for (unsigned i = tid; i < cnt; i += 512) {
        unsigned p = gb + i;
        if (p < CAP) candp[p] = cbuf[i];
    }
}

// ---------------------------------------------------------------------------
// T4: per-(b,lvl) bitonic sort of candidates, emit top-1000 scores + boxes
// ---------------------------------------------------------------------------
__global__ __launch_bounds__(1024) void sortemit_kernel(
    const float* __restrict__ boxes0, const float* __restrict__ boxes1,
    const float* __restrict__ boxes2, const float* __restrict__ boxes3,
    const unsigned* __restrict__ counters,
    const unsigned long long* __restrict__ cand,
    float* __restrict__ ws_scores,   // [32][1000]
    float* __restrict__ ws_boxes)    // [32][1000][4]
{
    const int blk = blockIdx.x;
    const int b   = blk >> 2;
    const int lvl = blk & 3;
    const int n   = lvl_n(lvl);
    const float* bx = lvl_boxes(boxes0, boxes1, boxes2, boxes3, lvl) + (size_t)b * n * 4;
    const unsigned long long* candp = cand + (size_t)blk * CAP;

    __shared__ unsigned long long arr[CAP];
    const int tid = threadIdx.x;
    unsigned cnt = counters[blk]; if (cnt > CAP) cnt = CAP;

    for (int i = tid; i < CAP; i += 1024)
        arr[i] = (i < (int)cnt) ? candp[i] : 0ull;
    __syncthreads();

    for (unsigned kk = 2; kk <= CAP; kk <<= 1) {
        for (unsigned j = kk >> 1; j > 0; j >>= 1) {
            for (unsigned i = tid; i < CAP; i += 1024) {
                unsigned p = i ^ j;
                if (p > i) {
                    unsigned long long a = arr[i], c = arr[p];
                    bool desc = ((i & kk) == 0);
                    if (desc ? (a < c) : (a > c)) { arr[i] = c; arr[p] = a; }
                }
            }
            __syncthreads();
        }
    }

    for (int r = tid; r < PRE_K; r += 1024) {
        unsigned long long c = arr[r];
        unsigned key = (unsigned)(c >> 32);
        int idx = (int)(~(unsigned)c);
        ws_scores[(size_t)blk * PRE_K + r] = key2f(key);
        float* dst = ws_boxes + ((size_t)blk * PRE_K + r) * 4;
        const float* src = bx + (size_t)idx * 4;
        dst[0] = src[0]; dst[1] = src[1]; dst[2] = src[2]; dst[3] = src[3];
    }
}

// ---------------------------------------------------------------------------
// Kernel 2a: mask build as 136 (word, row-block) 64x64 tile-tasks per level.
// Inner loop has NO LDS access (readlane broadcast; see R8 notes). Exact
// branchless threshold test in double. NEW: publishes per-chunk nonzero-row
// bitmaps (ws_nz, atomicOr) so greedy can visit only suppressor rows.
// ---------------------------------------------------------------------------
__global__ __launch_bounds__(256) void mask_kernel(
    const float* __restrict__ ws_boxes,
    unsigned long long* __restrict__ ws_mask,   // [32][1000][16]
    unsigned long long* __restrict__ ws_nz)     // [32][16]
{
    const int blk  = blockIdx.x / MBM;    // (b,lvl)
    const int mb   = blockIdx.x % MBM;
    const int tid  = threadIdx.x;
    const int lane = tid & 63;
    const int wv   = tid >> 6;            // wave 0..3

    __shared__ float4 sbox[1024];

    const float4* bxp = (const float4*)(ws_boxes + (size_t)blk * NB * 4);
    for (int i = tid; i < 1024; i += 256)
        sbox[i] = (i < NB) ? bxp[i] : make_float4(0.f, 0.f, 0.f, 0.f);
    __syncthreads();

    unsigned long long* maskp = ws_mask + (size_t)blk * NB * NW;
    unsigned long long* nzp   = ws_nz + (size_t)blk * NW;
    const double CSUM = (double)__uint_as_float(0x3F333333u)
                      + (double)__uint_as_float(0x3F333334u);   // exact 2*midpoint

    for (int t = mb * 4 + wv; t < 136; t += MBM * 4) {
        // decode t -> (w, rb): word w has row-blocks 0..w
        int w = 0, acc = 0;
        while (acc + w + 1 <= t) { acc += w + 1; ++w; }
        const int rb = t - acc;

        const int j = w * 64 + lane;
        const float4 jb = sbox[j];                    // zeros for j>=NB -> pred false
        const float aj = (jb.z - jb.x) * (jb.w - jb.y);

        const int rbase = rb * 64;
        const float4 rbx = sbox[rbase + lane];        // lane l owns row rbase+l
        const float ra = (rbx.z - rbx.x) * (rbx.w - rbx.y);
        const int ilim = min(64, NB - rbase);

        unsigned long long myw = 0ull;
        for (int i = 0; i < ilim; ++i) {
            const float y1 = bcast_f(rbx.x, i);
            const float x1 = bcast_f(rbx.y, i);
            const float y2 = bcast_f(rbx.z, i);
            const float x2 = bcast_f(rbx.w, i);
            const float ai = bcast_f(ra, i);
            float iy1 = fmaxf(y1, jb.x);
            float ix1 = fmaxf(x1, jb.y);
            float iy2 = fminf(y2, jb.z);
            float ix2 = fminf(x2, jb.w);
            float ih = fmaxf(iy2 - iy1, 0.0f);
            float iw = fmaxf(ix2 - ix1, 0.0f);
            float inter = ih * iw;
            float uni = ai + aj - inter;
            bool pred = (uni > 0.0f) &&
                        (2.0 * (double)inter >= CSUM * (double)uni) &&
                        (j > rbase + i);
            unsigned long long m = __ballot(pred);
            if (lane == i) myw = m;                   // cndmask, no branch
        }
        if (lane < ilim)
            maskp[(size_t)(rbase + lane) * NW + w] = myw;
        // nonzero-row bitmap for chunk rb (bit = row rbase+lane has bits in word w)
        unsigned long long nzb = __ballot(myw != 0ull);
        if (lane == 0 && nzb) atomicOr(&nzp[rb], nzb);
    }
}

// ---------------------------------------------------------------------------
// Kernel 2b: sparse greedy NMS. Only rows with NONZERO mask rows can change
// the keep state, so the serial recurrence visits just those rows (in order,
// re-checking each row's keep bit at its turn -- provably identical result).
// Candidate rows' mask words staged to LDS; 1-deep prefetch in the serial
// loop; sub-diagonal (unwritten/garbage) words masked by lane >= chunk.
// ---------------------------------------------------------------------------
__global__ __launch_bounds__(1024) void greedy_kernel(
    float* __restrict__ ws_scores,   // [32][1000] in-place
    float* __restrict__ ws_boxes,    // [32][1000][4] in-place
    const unsigned long long* __restrict__ ws_mask,
    const unsigned long long* __restrict__ ws_nz)
{
    const int blk  = blockIdx.x;
    const int tid  = threadIdx.x;
    const int lane = tid & 63;
    const int wv   = tid >> 6;       // 0..15

    __shared__ unsigned long long Mrow[NB * NW];     // 128000 B (worst case)
    __shared__ float4 sbox[NB];                      // 16000 B
    __shared__ float  ssc[NB];                       //  4000 B
    __shared__ unsigned long long nzlds[NW];
    __shared__ unsigned long long keepw[NW];
    __shared__ int wprefix[NW];
    __shared__ int slist[NB];                        // 4000 B
    __shared__ int sL;

    float* scp = ws_scores + (size_t)blk * NB;
    float* bxp = ws_boxes  + (size_t)blk * NB * 4;
    const unsigned long long* mrows = ws_mask + (size_t)blk * NB * NW;

    if (tid < NW) nzlds[tid] = ws_nz[(size_t)blk * NW + tid];
    for (int i = tid; i < NB; i += 1024) {
        sbox[i] = ((const float4*)bxp)[i];
        ssc[i]  = scp[i];
    }
    // initial keep bits: wave wv computes word wv
    {
        const int j = wv * 64 + lane;
        bool pred = (j < NB) && (scp[j] > 0.0f);
        unsigned long long bal = __ballot(pred);
        if (lane == 0) keepw[wv] = bal;
    }
    __syncthreads();

    // ---- ordered candidate (suppressor) row list ----
    if (tid == 0) {
        int L = 0;
        for (int c = 0; c < NW; ++c) {
            unsigned long long p = nzlds[c];
            while (p) {
                int i = __ffsll((long long)p) - 1;
                slist[L++] = c * 64 + i;
                p &= p - 1;
            }
        }
        sL = L;
    }
    __syncthreads();
    const int L = sL;

    // ---- stage candidate rows' mask words (sparse gather) ----
    for (int idx = tid; idx < L * NW; idx += 1024) {
        int r = slist[idx >> 4];
        Mrow[idx] = mrows[(size_t)r * NW + (idx & 15)];
    }
    __syncthreads();

    // ---- serial pass on wave 0, 1-deep prefetch ----
    if (tid < 64) {
        unsigned long long kp = (lane < NW) ? keepw[lane] : 0ull;
        unsigned long long mnext = (L > 0 && lane < NW) ? Mrow[lane] : 0ull;
        int rnext = (L > 0) ? slist[0] : 0;
        for (int k = 0; k < L; ++k) {
            unsigned long long m = mnext;
            const int r = rnext;
            if (k + 1 < L) {
                rnext = slist[k + 1];
                mnext = (lane < NW) ? Mrow[(size_t)(k + 1) * NW + lane] : 0ull;
            }
            const int c = r >> 6;
            unsigned klo = (unsigned)__builtin_amdgcn_readlane((int)(unsigned)kp, c);
            unsigned khi = (unsigned)__builtin_amdgcn_readlane((int)(unsigned)(kp >> 32), c);
            unsigned long long kw = ((unsigned long long)khi << 32) | klo;
            if ((kw >> (r & 63)) & 1ull) {           // row still kept -> applies
                unsigned long long mm = (lane >= c) ? m : 0ull;   // mask garbage words
                kp &= ~mm;
            }
        }
        if (lane < NW) keepw[lane] = kp;
    }
    __syncthreads();
    if (tid == 0) {
        int acc = 0;
        for (int w = 0; w < NW; ++w) { wprefix[w] = acc; acc += __popcll(keepw[w]); }
    }
    __syncthreads();

    // ---- zero-fill then stable scatter of survivors (from LDS copies) ----
    for (int i = tid; i < NB; i += 1024) scp[i] = 0.0f;
    for (int i = tid; i < NB * 4; i += 1024) bxp[i] = 0.0f;
    __syncthreads();
    for (int i = tid; i < NB; i += 1024) {
        const int w = i >> 6;
        const unsigned long long kw = keepw[w];
        if ((kw >> (i & 63)) & 1ull) {
            int rank = wprefix[w] + __popcll(kw & ((1ull << (i & 63)) - 1ull));
            scp[rank] = ssc[i];
            float4 bb = sbox[i];
            float* dst = bxp + (size_t)rank * 4;
            dst[0] = bb.x; dst[1] = bb.y; dst[2] = bb.z; dst[3] = bb.w;
        }
    }
}

// ---------------------------------------------------------------------------
// Kernel 3: final top-1000 by 4-way merge-rank. Each level's 1000-entry list
// is already sorted DESC by the exact final composite (score key, then
// concatenated index asc), so rank(e) = r + sum over other lists of
// count(> c) via binary search. Ranks unique -> scatter == full sort.
// One block per (b,lvl); batch's 4 lists staged in LDS (32 KB).
// ---------------------------------------------------------------------------
__global__ __launch_bounds__(1024) void final_merge_kernel(
    const float* __restrict__ ws_scores,  // [8][4][1000]
    const float* __restrict__ ws_boxes,   // [8][4000][4]
    float* __restrict__ out)              // rois (8*1000*4) then scores (8*1000)
{
    const int blk = blockIdx.x;          // b*4 + lvl
    const int b   = blk >> 2;
    const int lvl = blk & 3;
    const int tid = threadIdx.x;

    __shared__ unsigned long long lists[NLVL][PRE_K];   // 32000 B

    // stage all 4 lists of batch b as final composites
    for (int i = tid; i < TOT; i += 1024) {
        unsigned u = f2key(ws_scores[(size_t)b * TOT + i]);
        lists[i / PRE_K][i % PRE_K] =
            ((unsigned long long)u << 32) | (unsigned)(~i);
    }
    __syncthreads();

    float* out_rois   = out;            // (8,1000,4)
    float* out_scores = out + 32000;    // (8,1000)

    for (int r = tid; r < PRE_K; r += 1024) {
        const unsigned long long c = lists[lvl][r];
        int rank = r;
        #pragma unroll
        for (int l = 0; l < NLVL; ++l) {
            if (l == lvl) continue;
            // count of elements in descending lists[l] with composite > c
            int lo = 0, hi = PRE_K;
            while (lo < hi) {
                int mid = (lo + hi) >> 1;
                if (lists[l][mid] > c) lo = mid + 1; else hi = mid;
            }
            rank += lo;
        }
        if (rank < PRE_K) {
            out_scores[(size_t)b * PRE_K + rank] = key2f((unsigned)(c >> 32));
            const int pos = lvl * PRE_K + r;     // == ~(unsigned)c
            const float4 bb = ((const float4*)ws_boxes)[(size_t)b * TOT + pos];
            float* dst = out_rois + ((size_t)b * PRE_K + rank) * 4;
            dst[0] = bb.x; dst[1] = bb.y; dst[2] = bb.z; dst[3] = bb.w;
        }
    }
}

// ---------------------------------------------------------------------------
extern "C" void kernel_launch(void* const* d_in, const int* in_sizes, int n_in,
                              void* d_out, int out_size, void* d_ws, size_t ws_size,
                              hipStream_t stream) {
    // setup_inputs() dict order: boxes_p2, scores_p2, boxes_p3, scores_p3,
    //                            boxes_p4, scores_p4, boxes_p5, scores_p5
    const float* boxes0  = (const float*)d_in[0];
    const float* scores0 = (const float*)d_in[1];
    const float* boxes1  = (const float*)d_in[2];
    const float* scores1 = (const float*)d_in[3];
    const float* boxes2  = (const float*)d_in[4];
    const float* scores2 = (const float*)d_in[5];
    const float* boxes3  = (const float*)d_in[6];
    const float* scores3 = (const float*)d_in[7];
    float* out = (float*)d_out;

    // ws carve: scores [32*1000] | boxes [32*1000*4] | mask [32*1000*16 u64]
    //           | nz bitmaps [32*16 u64]
    // topk scratch (cand/ghist/counters/thresh) OVERLAYS the mask region:
    // all of it is dead before mask_kernel writes.
    char* base = (char*)d_ws;
    float* ws_scores = (float*)base;                                     // 128000 B
    float* ws_boxes  = (float*)(base + 128000);                          // 512000 B
    unsigned long long* ws_mask = (unsigned long long*)(base + 640000);  // 4096000 B
    unsigned long long* ws_nz   = (unsigned long long*)(base + 4736000); // 4096 B
    // overlay inside mask region:
    unsigned long long* cand = (unsigned long long*)(base + 640000);     // 524288 B
    unsigned* ghist    = (unsigned*)(base + 1164288);                    // 1048576 B
    unsigned* counters = (unsigned*)(base + 2212864);                    // 128 B
    unsigned* thresh   = (unsigned*)(base + 2212992);                    // 128 B

    init_kernel<<<128, 512, 0, stream>>>(ghist, ws_nz);
    hist_kernel<<<BATCH * NLVL * HB, 512, 0, stream>>>(
        scores0, scores1, scores2, scores3, ghist);
    select_kernel<<<BATCH * NLVL, 256, 0, stream>>>(ghist, thresh, counters);
    collect_kernel<<<BATCH * NLVL * HB, 512, 0, stream>>>(
        scores0, scores1, scores2, scores3, thresh, counters, cand);
    sortemit_kernel<<<BATCH * NLVL, 1024, 0, stream>>>(
        boxes0, boxes1, boxes2, boxes3, counters, cand, ws_scores, ws_boxes);
    mask_kernel<<<BATCH * NLVL * MBM, 256, 0, stream>>>(ws_boxes, ws_mask, ws_nz);
    greedy_kernel<<<BATCH * NLVL, 1024, 0, stream>>>(ws_scores, ws_boxes, ws_mask, ws_nz);
    final_merge_kernel<<<BATCH * NLVL, 1024, 0, stream>>>(ws_scores, ws_boxes, out);
}

// Round 10
// 110.418 us; speedup vs baseline: 4.0888x; 1.1517x over previous
//
#include <hip/hip_runtime.h>

#define PRE_K 1000
#define CAP   2048      // candidate buffer per level (>= PRE_K + max bin, pow2)
#define NBIN  8192      // 13-bit key-prefix histogram bins
#define NB    1000      // boxes per level after pre-NMS topk
#define NW    16        // 64-bit words covering NB bits (16*64 = 1024)
#define TOT   4000      // concatenated entries per batch
#define NLVL  4
#define BATCH 8
#define HB    8         // blocks per (b,lvl) for hist/collect
#define MBM   16        // blocks per (b,lvl) for mask build

__device__ __forceinline__ unsigned f2key(float f) {
    unsigned u = __float_as_uint(f);
    return (u & 0x80000000u) ? ~u : (u | 0x80000000u);   // monotonic ascending
}
__device__ __forceinline__ float key2f(unsigned k) {
    unsigned u = (k & 0x80000000u) ? (k & 0x7FFFFFFFu) : ~k;
    return __uint_as_float(u);
}
__device__ __forceinline__ const float* lvl_scores(
    const float* s0, const float* s1, const float* s2, const float* s3, int lvl) {
    switch (lvl) { case 0: return s0; case 1: return s1; case 2: return s2; default: return s3; }
}
__device__ __forceinline__ const float* lvl_boxes(
    const float* b0, const float* b1, const float* b2, const float* b3, int lvl) {
    switch (lvl) { case 0: return b0; case 1: return b1; case 2: return b2; default: return b3; }
}
__device__ __forceinline__ int lvl_n(int lvl) {
    const int sizes[4] = {196608, 49152, 12288, 3072};
    return sizes[lvl];
}
__device__ __forceinline__ float bcast_f(float v, int i) {
    return __int_as_float(__builtin_amdgcn_readlane(__float_as_int(v), i));
}

// ---------------------------------------------------------------------------
// T0: zero global histograms + nonzero-row bitmaps
// ---------------------------------------------------------------------------
__global__ __launch_bounds__(512) void init_kernel(
    unsigned* __restrict__ ghist, unsigned long long* __restrict__ ws_nz) {
    const int stride = gridDim.x * 512;
    for (int i = blockIdx.x * 512 + threadIdx.x; i < 32 * NBIN; i += stride)
        ghist[i] = 0u;
    for (int i = blockIdx.x * 512 + threadIdx.x; i < 32 * NW; i += stride)
        ws_nz[i] = 0ull;
}

// ---------------------------------------------------------------------------
// T1: per-(b,lvl) 13-bit-prefix histogram. float4 loads; 2 bank-replicas to
// halve hot-bin LDS atomic serialization (N(0,1) scores concentrate bins).
// ---------------------------------------------------------------------------
__global__ __launch_bounds__(512) void hist_kernel(
    const float* __restrict__ scores0, const float* __restrict__ scores1,
    const float* __restrict__ scores2, const float* __restrict__ scores3,
    unsigned* __restrict__ ghist)      // [32][NBIN]
{
    const int blk = blockIdx.x / HB;   // b*4 + lvl
    const int hb  = blockIdx.x % HB;
    const int b   = blk >> 2;
    const int lvl = blk & 3;
    const int n   = lvl_n(lvl);
    const float* sc = lvl_scores(scores0, scores1, scores2, scores3, lvl) + (size_t)b * n;

    __shared__ unsigned lhist[2][NBIN];   // 64 KB
    const int tid = threadIdx.x;
    const int rep = (tid >> 6) & 1;       // wave-uniform replica
    for (int i = tid; i < 2 * NBIN; i += 512) (&lhist[0][0])[i] = 0u;
    __syncthreads();

    const float4* sc4 = (const float4*)sc;
    const int n4 = n >> 2;                // all level sizes divisible by 4
    for (int i = hb * 512 + tid; i < n4; i += HB * 512) {
        float4 v = sc4[i];
        atomicAdd(&lhist[rep][f2key(v.x) >> 19], 1u);
        atomicAdd(&lhist[rep][f2key(v.y) >> 19], 1u);
        atomicAdd(&lhist[rep][f2key(v.z) >> 19], 1u);
        atomicAdd(&lhist[rep][f2key(v.w) >> 19], 1u);
    }
    __syncthreads();

    unsigned* gh = ghist + (size_t)blk * NBIN;
    for (int i = tid; i < NBIN; i += 512) {
        unsigned v = lhist[0][i] + lhist[1][i];
        if (v) atomicAdd(&gh[i], v);
    }
}

// ---------------------------------------------------------------------------
// T2: per-(b,lvl) threshold-bin selection (top-PRE_K boundary); zero counters
// ---------------------------------------------------------------------------
__global__ __launch_bounds__(256) void select_kernel(
    const unsigned* __restrict__ ghist,   // [32][NBIN]
    unsigned* __restrict__ thresh,        // [32]
    unsigned* __restrict__ counters)      // [32]
{
    const int blk = blockIdx.x;
    const int tid = threadIdx.x;
    const unsigned* gh = ghist + (size_t)blk * NBIN;

    __shared__ unsigned csum[256];
    __shared__ int s_chunk;
    __shared__ unsigned s_before;

    // chunk sums: thread t covers bins [t*32, t*32+32)
    unsigned s = 0;
    #pragma unroll 8
    for (int k = 0; k < 32; ++k) s += gh[tid * 32 + k];
    csum[tid] = s;
    __syncthreads();

    // suffix over chunks ABOVE tid (LDS broadcast reads)
    unsigned suf = 0;
    for (int c = tid + 1; c < 256; ++c) suf += csum[c];
    // unique chunk where the top-PRE_K boundary falls
    if (suf < PRE_K && suf + csum[tid] >= PRE_K) { s_chunk = tid; s_before = suf; }
    __syncthreads();

    if (tid == 0) {
        int C = s_chunk;
        unsigned acc = s_before;
        int T = C * 32;
        for (int bin = C * 32 + 31; bin >= C * 32; --bin) {
            acc += gh[bin];
            if (acc >= PRE_K) { T = bin; break; }
        }
        thresh[blk]   = (unsigned)T;
        counters[blk] = 0u;       // zero collect counter for this level
    }
}

// ---------------------------------------------------------------------------
// T3: collect candidates with key-bin >= threshold. LDS-buffered per block,
// ONE global atomic per block (order across blocks irrelevant: sorted later,
// stable tie-break lives in the composite key's ~idx).
// ---------------------------------------------------------------------------
__global__ __launch_bounds__(512) void collect_kernel(
    const float* __restrict__ scores0, const float* __restrict__ scores1,
    const float* __restrict__ scores2, const float* __restrict__ scores3,
    const unsigned* __restrict__ thresh,
    unsigned* __restrict__ counters,
    unsigned long long* __restrict__ cand)   // [32][CAP]
{
    const int blk = blockIdx.x / HB;
    const int hb  = blockIdx.x % HB;
    const int b   = blk >> 2;
    const int lvl = blk & 3;
    const int n   = lvl_n(lvl);
    const float* sc = lvl_scores(scores0, scores1, scores2, scores3, lvl) + (size_t)b * n;
    const unsigned T = thresh[blk];
    unsigned long long* candp = cand + (size_t)blk * CAP;

    __shared__ unsigned long long cbuf[CAP];
    __shared__ unsigned ccnt, cbase;

    const int tid  = threadIdx.x;
    const int lane = tid & 63;
    if (tid == 0) ccnt = 0;
    __syncthreads();

    for (int i = hb * 512 + tid; i < n; i += HB * 512) {
        unsigned key = f2key(sc[i]);
        bool pred = (key >> 19) >= T;
        unsigned long long act = __ballot(pred);
        if (act) {
            int leader = __ffsll((long long)act) - 1;
            unsigned base = 0;
            if (lane == leader) base = atomicAdd(&ccnt, (unsigned)__popcll(act));
            base = __shfl(base, leader, 64);
            if (pred) {
                unsigned pos = base + (unsigned)__popcll(act & ((1ull << lane) - 1ull));
                if (pos < CAP)
                    cbuf[pos] = ((unsigned long long)key << 32) | (unsigned)(~i);
            }
        }
    }
    __syncthreads();
    unsigned cnt = ccnt; if (cnt > CAP) cnt = CAP;
    if (tid == 0) cbase = atomicAdd(&counters[blk], cnt);
    __syncthreads();
    const unsigned gb = cbase;
    for (unsigned i = tid; i < cnt; i += 512) {
        unsigned p = gb + i;
        if (p < CAP) candp[p] = cbuf[i];
    }
}

// ---------------------------------------------------------------------------
// T4: per-(b,lvl) bitonic sort of candidates, emit top-1000 scores + boxes
// ---------------------------------------------------------------------------
__global__ __launch_bounds__(1024) void sortemit_kernel(
    const float* __restrict__ boxes0, const float* __restrict__ boxes1,
    const float* __restrict__ boxes2, const float* __restrict__ boxes3,
    const unsigned* __restrict__ counters,
    const unsigned long long* __restrict__ cand,
    float* __restrict__ ws_scores,   // [32][1000]
    float* __restrict__ ws_boxes)    // [32][1000][4]
{
    const int blk = blockIdx.x;
    const int b   = blk >> 2;
    const int lvl = blk & 3;
    const int n   = lvl_n(lvl);
    const float* bx = lvl_boxes(boxes0, boxes1, boxes2, boxes3, lvl) + (size_t)b * n * 4;
    const unsigned long long* candp = cand + (size_t)blk * CAP;

    __shared__ unsigned long long arr[CAP];
    const int tid = threadIdx.x;
    unsigned cnt = counters[blk]; if (cnt > CAP) cnt = CAP;

    for (int i = tid; i < CAP; i += 1024)
        arr[i] = (i < (int)cnt) ? candp[i] : 0ull;
    __syncthreads();

    for (unsigned kk = 2; kk <= CAP; kk <<= 1) {
        for (unsigned j = kk >> 1; j > 0; j >>= 1) {
            for (unsigned i = tid; i < CAP; i += 1024) {
                unsigned p = i ^ j;
                if (p > i) {
                    unsigned long long a = arr[i], c = arr[p];
                    bool desc = ((i & kk) == 0);
                    if (desc ? (a < c) : (a > c)) { arr[i] = c; arr[p] = a; }
                }
            }
            __syncthreads();
        }
    }

    for (int r = tid; r < PRE_K; r += 1024) {
        unsigned long long c = arr[r];
        unsigned key = (unsigned)(c >> 32);
        int idx = (int)(~(unsigned)c);
        ws_scores[(size_t)blk * PRE_K + r] = key2f(key);
        float* dst = ws_boxes + ((size_t)blk * PRE_K + r) * 4;
        const float* src = bx + (size_t)idx * 4;
        dst[0] = src[0]; dst[1] = src[1]; dst[2] = src[2]; dst[3] = src[3];
    }
}

// ---------------------------------------------------------------------------
// Kernel 2a: mask build, 136 (word, row-block) 64x64 tile-tasks per level.
// Lane owns a ROW and accumulates its own word (myw |= pred<<jj): no ballot,
// no lane-select in the loop. Fixed 64-iter fully-unrolled loop -> constant-
// index v_readlane broadcasts, full cross-iteration ILP (R9 lesson: dynamic
// trip count + dynamic readlane = serialized dependent chain). Zero-padded
// boxes make pred false for rows/cols >= NB (inter=0, uni>=0 fails test).
// Triangle guard is loop-free: off-diag tasks need none; diag tasks apply
// one post-loop mask (bits jj > lane). Exact branchless f64 threshold test:
// fl(inter/uni) > 0.7f  <=>  2*inter >= (c1+c2)*uni  (products <=49b exact).
// ---------------------------------------------------------------------------
__global__ __launch_bounds__(256) void mask_kernel(
    const float* __restrict__ ws_boxes,
    unsigned long long* __restrict__ ws_mask,   // [32][1000][16]
    unsigned long long* __restrict__ ws_nz)     // [32][16]
{
    const int blk  = blockIdx.x / MBM;    // (b,lvl)
    const int mb   = blockIdx.x % MBM;
    const int tid  = threadIdx.x;
    const int lane = tid & 63;
    const int wv   = tid >> 6;            // wave 0..3

    __shared__ float4 sbox[1024];

    const float4* bxp = (const float4*)(ws_boxes + (size_t)blk * NB * 4);
    for (int i = tid; i < 1024; i += 256)
        sbox[i] = (i < NB) ? bxp[i] : make_float4(0.f, 0.f, 0.f, 0.f);
    __syncthreads();

    unsigned long long* maskp = ws_mask + (size_t)blk * NB * NW;
    unsigned long long* nzp   = ws_nz + (size_t)blk * NW;
    const double CSUM = (double)__uint_as_float(0x3F333333u)
                      + (double)__uint_as_float(0x3F333334u);   // exact 2*midpoint

    for (int t = mb * 4 + wv; t < 136; t += MBM * 4) {
        // decode t -> (w, rb): word w has row-blocks 0..w
        int w = 0, acc = 0;
        while (acc + w + 1 <= t) { acc += w + 1; ++w; }
        const int rb = t - acc;
        const int rbase = rb * 64;

        const float4 rbx = sbox[rbase + lane];     // lane's ROW box
        const float   ra = (rbx.z - rbx.x) * (rbx.w - rbx.y);
        const float4 cbx = sbox[w * 64 + lane];    // lane's slot of COL boxes
        const float   ca = (cbx.z - cbx.x) * (cbx.w - cbx.y);

        unsigned long long myw = 0ull;
        #pragma unroll
        for (int jj = 0; jj < 64; ++jj) {
            const float cy1 = bcast_f(cbx.x, jj);
            const float cx1 = bcast_f(cbx.y, jj);
            const float cy2 = bcast_f(cbx.z, jj);
            const float cx2 = bcast_f(cbx.w, jj);
            const float caj = bcast_f(ca, jj);
            float iy1 = fmaxf(rbx.x, cy1);
            float ix1 = fmaxf(rbx.y, cx1);
            float iy2 = fminf(rbx.z, cy2);
            float ix2 = fminf(rbx.w, cx2);
            float ih = fmaxf(iy2 - iy1, 0.0f);
            float iw = fmaxf(ix2 - ix1, 0.0f);
            float inter = ih * iw;
            float uni = ra + caj - inter;
            bool pred = (uni > 0.0f) &&
                        (2.0 * (double)inter >= CSUM * (double)uni);
            myw |= ((unsigned long long)pred) << jj;
        }
        if (w == rb)
            myw &= ~((2ull << lane) - 1ull);       // keep only jj > lane (lane63 -> 0)
        if (rbase + lane < NB)
            maskp[(size_t)(rbase + lane) * NW + w] = myw;
        // nonzero-row bitmap for chunk rb
        unsigned long long nzb = __ballot(myw != 0ull);
        if (lane == 0 && nzb) atomicOr(&nzp[rb], nzb);
    }
}

// ---------------------------------------------------------------------------
// Kernel 2b: sparse greedy NMS. Only rows with NONZERO mask rows can change
// the keep state, so the serial recurrence visits just those rows (in order,
// re-checking each row's keep bit at its turn -- provably identical result).
// Candidate rows' mask words staged to LDS; 1-deep prefetch in the serial
// loop; sub-diagonal (unwritten/garbage) words masked by lane >= chunk.
// ---------------------------------------------------------------------------
__global__ __launch_bounds__(1024) void greedy_kernel(
    float* __restrict__ ws_scores,   // [32][1000] in-place
    float* __restrict__ ws_boxes,    // [32][1000][4] in-place
    const unsigned long long* __restrict__ ws_mask,
    const unsigned long long* __restrict__ ws_nz)
{
    const int blk  = blockIdx.x;
    const int tid  = threadIdx.x;
    const int lane = tid & 63;
    const int wv   = tid >> 6;       // 0..15

    __shared__ unsigned long long Mrow[NB * NW];     // 128000 B (worst case)
    __shared__ float4 sbox[NB];                      // 16000 B
    __shared__ float  ssc[NB];                       //  4000 B
    __shared__ unsigned long long nzlds[NW];
    __shared__ unsigned long long keepw[NW];
    __shared__ int wprefix[NW];
    __shared__ int slist[NB];                        // 4000 B
    __shared__ int sL;

    float* scp = ws_scores + (size_t)blk * NB;
    float* bxp = ws_boxes  + (size_t)blk * NB * 4;
    const unsigned long long* mrows = ws_mask + (size_t)blk * NB * NW;

    if (tid < NW) nzlds[tid] = ws_nz[(size_t)blk * NW + tid];
    for (int i = tid; i < NB; i += 1024) {
        sbox[i] = ((const float4*)bxp)[i];
        ssc[i]  = scp[i];
    }
    // initial keep bits: wave wv computes word wv
    {
        const int j = wv * 64 + lane;
        bool pred = (j < NB) && (scp[j] > 0.0f);
        unsigned long long bal = __ballot(pred);
        if (lane == 0) keepw[wv] = bal;
    }
    __syncthreads();

    // ---- ordered candidate (suppressor) row list ----
    if (tid == 0) {
        int L = 0;
        for (int c = 0; c < NW; ++c) {
            unsigned long long p = nzlds[c];
            while (p) {
                int i = __ffsll((long long)p) - 1;
                slist[L++] = c * 64 + i;
                p &= p - 1;
            }
        }
        sL = L;
    }
    __syncthreads();
    const int L = sL;

    // ---- stage candidate rows' mask words (sparse gather) ----
    for (int idx = tid; idx < L * NW; idx += 1024) {
        int r = slist[idx >> 4];
        Mrow[idx] = mrows[(size_t)r * NW + (idx & 15)];
    }
    __syncthreads();

    // ---- serial pass on wave 0, 1-deep prefetch ----
    if (tid < 64) {
        unsigned long long kp = (lane < NW) ? keepw[lane] : 0ull;
        unsigned long long mnext = (L > 0 && lane < NW) ? Mrow[lane] : 0ull;
        int rnext = (L > 0) ? slist[0] : 0;
        for (int k = 0; k < L; ++k) {
            unsigned long long m = mnext;
            const int r = rnext;
            if (k + 1 < L) {
                rnext = slist[k + 1];
                mnext = (lane < NW) ? Mrow[(size_t)(k + 1) * NW + lane] : 0ull;
            }
            const int c = r >> 6;
            unsigned klo = (unsigned)__builtin_amdgcn_readlane((int)(unsigned)kp, c);
            unsigned khi = (unsigned)__builtin_amdgcn_readlane((int)(unsigned)(kp >> 32), c);
            unsigned long long kw = ((unsigned long long)khi << 32) | klo;
            if ((kw >> (r & 63)) & 1ull) {           // row still kept -> applies
                unsigned long long mm = (lane >= c) ? m : 0ull;   // mask garbage words
                kp &= ~mm;
            }
        }
        if (lane < NW) keepw[lane] = kp;
    }
    __syncthreads();
    if (tid == 0) {
        int acc = 0;
        for (int w = 0; w < NW; ++w) { wprefix[w] = acc; acc += __popcll(keepw[w]); }
    }
    __syncthreads();

    // ---- zero-fill then stable scatter of survivors (from LDS copies) ----
    for (int i = tid; i < NB; i += 1024) scp[i] = 0.0f;
    for (int i = tid; i < NB * 4; i += 1024) bxp[i] = 0.0f;
    __syncthreads();
    for (int i = tid; i < NB; i += 1024) {
        const int w = i >> 6;
        const unsigned long long kw = keepw[w];
        if ((kw >> (i & 63)) & 1ull) {
            int rank = wprefix[w] + __popcll(kw & ((1ull << (i & 63)) - 1ull));
            scp[rank] = ssc[i];
            float4 bb = sbox[i];
            float* dst = bxp + (size_t)rank * 4;
            dst[0] = bb.x; dst[1] = bb.y; dst[2] = bb.z; dst[3] = bb.w;
        }
    }
}

// ---------------------------------------------------------------------------
// Kernel 3: final top-1000 by 4-way merge-rank. Each level's 1000-entry list
// is already sorted DESC by the exact final composite (score key, then
// concatenated index asc), so rank(e) = r + sum over other lists of
// count(> c) via binary search. Ranks unique -> scatter == full sort.
// One block per (b,lvl); batch's 4 lists staged in LDS (32 KB).
// ---------------------------------------------------------------------------
__global__ __launch_bounds__(1024) void final_merge_kernel(
    const float* __restrict__ ws_scores,  // [8][4][1000]
    const float* __restrict__ ws_boxes,   // [8][4000][4]
    float* __restrict__ out)              // rois (8*1000*4) then scores (8*1000)
{
    const int blk = blockIdx.x;          // b*4 + lvl
    const int b   = blk >> 2;
    const int lvl = blk & 3;
    const int tid = threadIdx.x;

    __shared__ unsigned long long lists[NLVL][PRE_K];   // 32000 B

    // stage all 4 lists of batch b as final composites
    for (int i = tid; i < TOT; i += 1024) {
        unsigned u = f2key(ws_scores[(size_t)b * TOT + i]);
        lists[i / PRE_K][i % PRE_K] =
            ((unsigned long long)u << 32) | (unsigned)(~i);
    }
    __syncthreads();

    float* out_rois   = out;            // (8,1000,4)
    float* out_scores = out + 32000;    // (8,1000)

    for (int r = tid; r < PRE_K; r += 1024) {
        const unsigned long long c = lists[lvl][r];
        int rank = r;
        #pragma unroll
        for (int l = 0; l < NLVL; ++l) {
            if (l == lvl) continue;
            // count of elements in descending lists[l] with composite > c
            int lo = 0, hi = PRE_K;
            while (lo < hi) {
                int mid = (lo + hi) >> 1;
                if (lists[l][mid] > c) lo = mid + 1; else hi = mid;
            }
            rank += lo;
        }
        if (rank < PRE_K) {
            out_scores[(size_t)b * PRE_K + rank] = key2f((unsigned)(c >> 32));
            const int pos = lvl * PRE_K + r;     // == ~(unsigned)c
            const float4 bb = ((const float4*)ws_boxes)[(size_t)b * TOT + pos];
            float* dst = out_rois + ((size_t)b * PRE_K + rank) * 4;
            dst[0] = bb.x; dst[1] = bb.y; dst[2] = bb.z; dst[3] = bb.w;
        }
    }
}

// ---------------------------------------------------------------------------
extern "C" void kernel_launch(void* const* d_in, const int* in_sizes, int n_in,
                              void* d_out, int out_size, void* d_ws, size_t ws_size,
                              hipStream_t stream) {
    // setup_inputs() dict order: boxes_p2, scores_p2, boxes_p3, scores_p3,
    //                            boxes_p4, scores_p4, boxes_p5, scores_p5
    const float* boxes0  = (const float*)d_in[0];
    const float* scores0 = (const float*)d_in[1];
    const float* boxes1  = (const float*)d_in[2];
    const float* scores1 = (const float*)d_in[3];
    const float* boxes2  = (const float*)d_in[4];
    const float* scores2 = (const float*)d_in[5];
    const float* boxes3  = (const float*)d_in[6];
    const float* scores3 = (const float*)d_in[7];
    float* out = (float*)d_out;

    // ws carve: scores [32*1000] | boxes [32*1000*4] | mask [32*1000*16 u64]
    //           | nz bitmaps [32*16 u64]
    // topk scratch (cand/ghist/counters/thresh) OVERLAYS the mask region:
    // all of it is dead before mask_kernel writes.
    char* base = (char*)d_ws;
    float* ws_scores = (float*)base;                                     // 128000 B
    float* ws_boxes  = (float*)(base + 128000);                          // 512000 B
    unsigned long long* ws_mask = (unsigned long long*)(base + 640000);  // 4096000 B
    unsigned long long* ws_nz   = (unsigned long long*)(base + 4736000); // 4096 B
    // overlay inside mask region:
    unsigned long long* cand = (unsigned long long*)(base + 640000);     // 524288 B
    unsigned* ghist    = (unsigned*)(base + 1164288);                    // 1048576 B
    unsigned* counters = (unsigned*)(base + 2212864);                    // 128 B
    unsigned* thresh   = (unsigned*)(base + 2212992);                    // 128 B

    init_kernel<<<128, 512, 0, stream>>>(ghist, ws_nz);
    hist_kernel<<<BATCH * NLVL * HB, 512, 0, stream>>>(
        scores0, scores1, scores2, scores3, ghist);
    select_kernel<<<BATCH * NLVL, 256, 0, stream>>>(ghist, thresh, counters);
    collect_kernel<<<BATCH * NLVL * HB, 512, 0, stream>>>(
        scores0, scores1, scores2, scores3, thresh, counters, cand);
    sortemit_kernel<<<BATCH * NLVL, 1024, 0, stream>>>(
        boxes0, boxes1, boxes2, boxes3, counters, cand, ws_scores, ws_boxes);
    mask_kernel<<<BATCH * NLVL * MBM, 256, 0, stream>>>(ws_boxes, ws_mask, ws_nz);
    greedy_kernel<<<BATCH * NLVL, 1024, 0, stream>>>(ws_scores, ws_boxes, ws_mask, ws_nz);
    final_merge_kernel<<<BATCH * NLVL, 1024, 0, stream>>>(ws_scores, ws_boxes, out);
}